// Round 4
// baseline (260.865 us; speedup 1.0000x reference)
//
#include <hip/hip_runtime.h>
#include <hip/hip_fp16.h>
#include <hip/hip_bf16.h>
#include <stdint.h>

#define WN 343       // tokens per window
#define NH 6         // heads
#define HD 32        // head dim
#define CD 192       // channels
#define NB 128       // windows (batch)
#define NWM 32       // mask windows
#define BMROW 352            // padded query dim
#define BMSLICE (11*16*BMROW) // dwords per (wdx,h) slice = 61952
#define BMKC (16*BMROW)       // dwords per kc chunk = 5632
#define LOG2E 1.4426950408889634f

typedef __attribute__((ext_vector_type(8))) short short8;
typedef __attribute__((ext_vector_type(4))) float f32x4;

__device__ __forceinline__ unsigned short f2bf(float f) {
  union { float f; uint32_t u; } v; v.f = f;
  uint32_t r = v.u + 0x7fffu + ((v.u >> 16) & 1u);
  return (unsigned short)(r >> 16);
}

// packed f32x2 -> bf16x2 (v_cvt_pk_bf16_f32 on gfx950); low half = a
__device__ __forceinline__ uint32_t pk2bf(float a, float b) {
  __hip_bfloat162 h = __float22bfloat162_rn(make_float2(a, b));
  return *(uint32_t*)&h;
}

__device__ __forceinline__ uint32_t pkh2(float a, float b) {
  __half2 h; h.x = __float2half(a); h.y = __float2half(b);
  return *(uint32_t*)&h;
}

// async global->LDS, 16B per lane; LDS dest is wave-uniform base + lane*16
typedef const __attribute__((address_space(1))) unsigned int* gas_ptr;
typedef __attribute__((address_space(3))) unsigned int* las_ptr;
__device__ __forceinline__ void gload16(const unsigned short* g, unsigned short* l) {
  __builtin_amdgcn_global_load_lds((gas_ptr)(const void*)g, (las_ptr)(void*)l, 16, 0, 0);
}

// ---------------- prep: bm fuse (352) | wq swizzle (54) | wp swizzle (18) |
// x swizzle-cvt (4116).
// bm branch (r4): one block per (wdx,kc) computes (bias+mask)*log2e for ALL
// 6 heads -> bmP[(wdx*6+h)] slices, f16x2 word (quad,n,r) =
// (bm[n][q8+r], bm[n][q8+r+4]). attn then loads ONE dwordx4 per kc (was two
// + 4 hadd2). mask (f16) + rel (u16) staged once in LDS, heads amortized.
// OOB keys: -30000 (exp2 -> 0).
// wq/wp/x swizzled-tile layout: per 32-k tile, row-major 64B rows, 16B
// chunks permuted cc = lch ^ ((row>>1)&3); consumers stage LINEARLY via
// global_load_lds and read fragments at chunk (quad ^ ((c>>1)&3)).
__global__ __launch_bounds__(256) void prep_kernel(
    const float* __restrict__ wq, const float* __restrict__ wp,
    unsigned short* __restrict__ wqb, unsigned short* __restrict__ wpb,
    const int* __restrict__ rel, const float* __restrict__ rpb,
    const float* __restrict__ mask, uint32_t* __restrict__ bmP,
    const float* __restrict__ x, unsigned short* __restrict__ xb) {
  const int bid = blockIdx.x;
  const int tid = threadIdx.x;
  if (bid < 352) {
    __shared__ __half M16[352][33];       // mask chunk (f16, = old precision)
    __shared__ unsigned short R[WN][33];  // rel chunk (values < 2197)
    const int wdx = bid / 11;
    const int kc = bid - wdx * 11;
    const int k0 = kc * 32;
    const float* mw = mask + (size_t)wdx * (WN * WN);
    for (int idx = tid; idx < 352 * 32; idx += 256) {
      int n = idx >> 5, k = idx & 31;
      float v = (n < WN && k0 + k < WN) ? mw[n * WN + k0 + k] : 0.0f;
      M16[n][k] = __float2half(v);
    }
    for (int idx = tid; idx < WN * 32; idx += 256) {
      int n = idx >> 5, k = idx & 31;
      R[n][k] = (unsigned short)((k0 + k < WN) ? rel[n * WN + k0 + k] : 0);
    }
    __syncthreads();
    uint32_t* outB = bmP + (size_t)(wdx * 6) * BMSLICE + (size_t)kc * BMKC;
#pragma unroll
    for (int quad = 0; quad < 4; ++quad) {
      const int q8 = quad * 8;
#pragma unroll
      for (int j = 0; j < 2; ++j) {
        int n = tid + 256 * j;
        if (n < 352) {
          int nc = (n < WN) ? n : (WN - 1);
          float vA[4], vB[4]; int rA[4], rB[4]; bool oA[4], oB[4];
#pragma unroll
          for (int r = 0; r < 4; ++r) {
            vA[r] = __half2float(M16[n][q8 + r]);
            vB[r] = __half2float(M16[n][q8 + r + 4]);
            rA[r] = (int)R[nc][q8 + r] * NH;
            rB[r] = (int)R[nc][q8 + r + 4] * NH;
            oA[r] = (k0 + q8 + r) < WN;
            oB[r] = (k0 + q8 + r + 4) < WN;
          }
#pragma unroll
          for (int h = 0; h < 6; ++h) {
            float a[4], b[4];
#pragma unroll
            for (int r = 0; r < 4; ++r) {
              a[r] = oA[r] ? (vA[r] + rpb[rA[r] + h]) * LOG2E : -30000.0f;
              b[r] = oB[r] ? (vB[r] + rpb[rB[r] + h]) * LOG2E : -30000.0f;
            }
            uint4 o;
            o.x = pkh2(a[0], b[0]);
            o.y = pkh2(a[1], b[1]);
            o.z = pkh2(a[2], b[2]);
            o.w = pkh2(a[3], b[3]);
            *(uint4*)(outB + (size_t)h * BMSLICE + ((size_t)quad * 352 + n) * 4) = o;
          }
        }
      }
    }
    return;
  }
  int cb = bid - 352;
  if (cb < 54) {
    // wq -> swizzled bf16 tiles: 18 tiles (s*6+kt) x 192 rows x 4 chunks
    int g = cb * 256 + tid;            // < 13824
    int sk = g / 768; int rem = g - sk * 768;
    int row = rem >> 2; int cc = rem & 3;
    int s = sk / 6; int kt = sk - s * 6;
    int lch = cc ^ ((row >> 1) & 3);
    const float* src = wq + (size_t)(s * 192 + row) * CD + kt * 32 + lch * 8;
    f32x4 a = *(const f32x4*)src;
    f32x4 b = *(const f32x4*)(src + 4);
    union { short8 v8; uint32_t d[4]; } pk;
    pk.d[0] = pk2bf(a[0], a[1]);
    pk.d[1] = pk2bf(a[2], a[3]);
    pk.d[2] = pk2bf(b[0], b[1]);
    pk.d[3] = pk2bf(b[2], b[3]);
    *(short8*)(wqb + (size_t)g * 8) = pk.v8;
    return;
  }
  cb -= 54;
  if (cb < 18) {
    // wp -> swizzled bf16 tiles: 6 tiles (kt) x 192 rows x 4 chunks
    int g = cb * 256 + tid;            // < 4608
    int kt = g / 768; int rem = g - kt * 768;
    int row = rem >> 2; int cc = rem & 3;
    int lch = cc ^ ((row >> 1) & 3);
    const float* src = wp + (size_t)row * CD + kt * 32 + lch * 8;
    f32x4 a = *(const f32x4*)src;
    f32x4 b = *(const f32x4*)(src + 4);
    union { short8 v8; uint32_t d[4]; } pk;
    pk.d[0] = pk2bf(a[0], a[1]);
    pk.d[1] = pk2bf(a[2], a[3]);
    pk.d[2] = pk2bf(b[0], b[1]);
    pk.d[3] = pk2bf(b[2], b[3]);
    *(short8*)(wpb + (size_t)g * 8) = pk.v8;
    return;
  }
  cb -= 18;
  // x -> swizzled bf16 tiles: 343*6 tiles x 128 rows x 4 chunks
  size_t gx = (size_t)cb * 256 + tid;  // < 1,053,696
  int tile = (int)(gx >> 9); int rem = (int)(gx & 511);
  int row = rem >> 2; int cc = rem & 3;
  int mb = tile / 6; int kt = tile - mb * 6;
  int lch = cc ^ ((row >> 1) & 3);
  const float* src = x + ((size_t)mb * 128 + row) * CD + kt * 32 + lch * 8;
  f32x4 a = *(const f32x4*)src;
  f32x4 b = *(const f32x4*)(src + 4);
  union { short8 v8; uint32_t d[4]; } pk;
  pk.d[0] = pk2bf(a[0], a[1]);
  pk.d[1] = pk2bf(a[2], a[3]);
  pk.d[2] = pk2bf(b[0], b[1]);
  pk.d[3] = pk2bf(b[2], b[3]);
  *(short8*)(xb + gx * 8) = pk.v8;
}

// ---------------- QKV GEMM (r3 structure, unchanged): 128x192 tile, 6
// ktiles, 2 barriers each, staging via global_load_lds width-16 from the
// pre-swizzled bf16 xb/wqb. Epilogue repack (stride 36) overlays staging LDS.
__global__ __launch_bounds__(256) void qkv_kernel(
    const unsigned short* __restrict__ xb, const unsigned short* __restrict__ wqb,
    const float* __restrict__ bvec,
    unsigned short* __restrict__ qb, unsigned short* __restrict__ kb,
    unsigned short* __restrict__ vb) {
  __shared__ __align__(16) unsigned short SL[10240];   // 20KB
  unsigned short* XL = SL;            // 128x32 linear (swizzled chunks)
  unsigned short* WL = SL + 4096;     // 192x32 linear
  const int tid = threadIdx.x;
  const int wave = tid >> 6, lane = tid & 63;
  const int quad = lane >> 4, c = lane & 15;
  const int m0 = blockIdx.x * 128;
  const int s = blockIdx.y;            // 0=q, 1=k, 2=v
  const int chk = (quad ^ ((c >> 1) & 3)) * 8;

  f32x4 acc[2][12];
#pragma unroll
  for (int i = 0; i < 2; ++i)
#pragma unroll
    for (int j = 0; j < 12; ++j) acc[i][j] = (f32x4){0.f, 0.f, 0.f, 0.f};

  const size_t xt0 = (size_t)blockIdx.x * 6;
  const size_t wt0 = (size_t)s * 6;
  for (int kt = 0; kt < 6; ++kt) {
    const unsigned short* gx = xb + ((xt0 + kt) << 12) + tid * 8;
    const unsigned short* gw = wqb + (wt0 + kt) * 6144 + tid * 8;
    unsigned short* lx = XL + (size_t)wave * 512;   // wave-uniform, 1KB/wave
    unsigned short* lw = WL + (size_t)wave * 512;
    gload16(gx, lx);
    gload16(gx + 2048, lx + 2048);
    gload16(gw, lw);
    gload16(gw + 2048, lw + 2048);
    gload16(gw + 4096, lw + 4096);
    __syncthreads();
    short8 af0 = *(const short8*)&XL[(wave * 32 + c) * 32 + chk];
    short8 af1 = *(const short8*)&XL[(wave * 32 + 16 + c) * 32 + chk];
#pragma unroll
    for (int j = 0; j < 12; ++j) {
      short8 bfr = *(const short8*)&WL[(j * 16 + c) * 32 + chk];
      acc[0][j] = __builtin_amdgcn_mfma_f32_16x16x32_bf16(af0, bfr, acc[0][j], 0, 0, 0);
      acc[1][j] = __builtin_amdgcn_mfma_f32_16x16x32_bf16(af1, bfr, acc[1][j], 0, 0, 0);
    }
    __syncthreads();
  }

  // q scale folded with log2(e): 32^-0.5 * 1.4426950409 (softmax runs in
  // exp2 domain; bm pre-scaled by log2(e) in prep)
  const float qscale = 0.25503486f;
  unsigned short* dst = (s == 0) ? qb : ((s == 1) ? kb : vb);
  const float scl = (s == 0) ? qscale : 1.0f;
  const int n0 = s * 192;
  // repack overlays dead staging LDS; stride 36 shorts -> all-32-bank writes
  unsigned short* Lh0 = SL;            // 128 rows x 36
  unsigned short* Lh1 = SL + 4608;
  for (int hh = 0; hh < 3; ++hh) {
    __syncthreads();
#pragma unroll
    for (int jj = 0; jj < 4; ++jj) {
      int j = hh * 4 + jj;
      int hl = jj >> 1;
      int dd = (jj & 1) * 16 + c;
      float bn = bvec[n0 + j * 16 + c];
      unsigned short* L = hl ? Lh1 : Lh0;
#pragma unroll
      for (int i = 0; i < 2; ++i)
#pragma unroll
        for (int r = 0; r < 4; ++r) {
          int m = wave * 32 + i * 16 + quad * 4 + r;
          L[m * 36 + dd] = f2bf((acc[i][j][r] + bn) * scl);
        }
    }
    __syncthreads();
    const int m = tid & 127;
    const int hl = tid >> 7;
    const int M = m0 + m;
    const int b = M / WN;
    const int tok = M - b * WN;
    const int h = hh * 2 + hl;
    const unsigned short* L = hl ? Lh1 : Lh0;
    unsigned short* drow = dst + (((size_t)b * NH + h) * WN + tok) * HD;
#pragma unroll
    for (int t2 = 0; t2 < 4; ++t2) {
      int d0 = t2 * 8;
      *(short8*)&drow[d0] = *(const short8*)&L[m * 36 + d0];
    }
  }
}

// ---------------- fused attention (r4): single streaming loop, no max-sub.
// 512 threads (8 waves); LDS 51KB. XCD-aware remap: 24 blocks sharing one
// mask slice land on the SAME XCD. Per kc the C-operand is now ONE dwordx4
// from the fused bm buffer (bias+mask pre-summed+log2e-scaled in prep) ->
// per-kc chain loses one dependent L2 load + 4 hadd2, and ~44 VGPRs of
// hoisted mask words are freed for deeper prefetch. O is stored in the
// swizzled tile layout proj stages with global_load_lds (kt == head).
// NOTE: plain __launch_bounds__ — a min-waves arg makes the allocator cap
// VGPRs and spill (r5: +29MB).
__global__ __launch_bounds__(512) void attn_kernel(
    const unsigned short* __restrict__ qb, const unsigned short* __restrict__ kb,
    const unsigned short* __restrict__ vb, const uint32_t* __restrict__ bmP,
    unsigned short* __restrict__ ob) {
  __shared__ __align__(16) unsigned short Ks[352][40];  // [perm key row][d]
  __shared__ __align__(16) unsigned short Vt[HD][360];  // [d][key]
  // XCD swizzle: bid%8 = XCD (observed round-robin); job groups of 24 share wdx
  const int bid = blockIdx.x;
  const int job = (bid & 7) * 96 + (bid >> 3);
  const int wdx = job / 24;
  const int inner = job - wdx * 24;
  const int h = inner >> 2;
  const int b = (inner & 3) * 32 + wdx;   // preserves wdx == b & 31
  const int tid = threadIdx.x;
  const int wave = tid >> 6, lane = tid & 63;
  const int quad = lane >> 4, c = lane & 15;
  const size_t base = ((size_t)b * NH + h) * (WN * HD);
  const unsigned short* q = qb + base;
  const unsigned short* k = kb + base;
  const unsigned short* v = vb + base;
  const uint32_t* bmS = bmP + (size_t)(wdx * 6 + h) * BMSLICE;

  // stage K with permuted rows
  for (int t = tid; t < WN * 4; t += 512) {
    int r = t >> 2, ch = t & 3;
    int kk = r & 31;
    int row = (r & ~31) + 16 * ((kk >> 2) & 1) + 4 * (kk >> 3) + (kk & 3);
    *(short8*)&Ks[row][ch * 8] = *(const short8*)(k + r * HD + ch * 8);
  }
  for (int t = tid; t < 9 * 32; t += 512) {
    int kg = WN + (t >> 5);
    int kk = kg & 31;
    int row = (kg & ~31) + 16 * ((kk >> 2) & 1) + 4 * (kk >> 3) + (kk & 3);
    Ks[row][t & 31] = 0;
  }
  // stage V transposed, natural key order
  for (int t = tid; t < WN; t += 512) {
#pragma unroll
    for (int ch = 0; ch < 4; ++ch) {
      short8 vv = *(const short8*)(v + t * HD + ch * 8);
#pragma unroll
      for (int j = 0; j < 8; ++j) Vt[ch * 8 + j][t] = vv[j];
    }
  }
  for (int t = tid; t < 9 * 32; t += 512) {
    Vt[t & 31][WN + (t >> 5)] = 0;
  }
  __syncthreads();

  for (int qt = wave; qt < 22; qt += 8) {
    const int q0 = qt * 16;
    int qr = q0 + c; if (qr > WN - 1) qr = WN - 1;
    const short8 qf = *(const short8*)(q + qr * HD + quad * 8);
    const uint32_t* bmRow = bmS + ((size_t)quad * 352 + q0 + c) * 4;

    f32x4 o0 = (f32x4){0.f, 0.f, 0.f, 0.f}, o1 = (f32x4){0.f, 0.f, 0.f, 0.f};
    float l = 0.f;
#pragma unroll
    for (int kc = 0; kc < 11; ++kc) {
      // C-operand = log2e*(bias+mask) for this lane's 8 keys: ONE dwordx4
      uint4 w4 = *(const uint4*)(bmRow + (size_t)kc * BMKC);
      f32x4 cc0, cc1;
      {
        float2 f;
        f = __half22float2(*(__half2*)&w4.x); cc0[0] = f.x; cc1[0] = f.y;
        f = __half22float2(*(__half2*)&w4.y); cc0[1] = f.x; cc1[1] = f.y;
        f = __half22float2(*(__half2*)&w4.z); cc0[2] = f.x; cc1[2] = f.y;
        f = __half22float2(*(__half2*)&w4.w); cc0[3] = f.x; cc1[3] = f.y;
      }
      const int k0 = kc * 32;
      short8 kf0 = *(const short8*)&Ks[k0 + c][quad * 8];
      short8 kf1 = *(const short8*)&Ks[k0 + 16 + c][quad * 8];
      f32x4 s0 = __builtin_amdgcn_mfma_f32_16x16x32_bf16(kf0, qf, cc0, 0, 0, 0);
      f32x4 s1 = __builtin_amdgcn_mfma_f32_16x16x32_bf16(kf1, qf, cc1, 0, 0, 0);
      // scores are in log2 domain -> direct v_exp_f32 (2^x), unnormalized;
      // OOB keys carry -30000 -> exp2==0
      float p0 = __builtin_amdgcn_exp2f(s0[0]), p1 = __builtin_amdgcn_exp2f(s0[1]);
      float p2 = __builtin_amdgcn_exp2f(s0[2]), p3 = __builtin_amdgcn_exp2f(s0[3]);
      float p4 = __builtin_amdgcn_exp2f(s1[0]), p5 = __builtin_amdgcn_exp2f(s1[1]);
      float p6 = __builtin_amdgcn_exp2f(s1[2]), p7 = __builtin_amdgcn_exp2f(s1[3]);
      l += (p0 + p1 + p2 + p3) + (p4 + p5 + p6 + p7);
      union { short8 v8; uint32_t d[4]; } pf;
      pf.d[0] = pk2bf(p0, p1);
      pf.d[1] = pk2bf(p2, p3);
      pf.d[2] = pk2bf(p4, p5);
      pf.d[3] = pk2bf(p6, p7);
      short8 vf0 = *(const short8*)&Vt[c][k0 + quad * 8];
      short8 vf1 = *(const short8*)&Vt[16 + c][k0 + quad * 8];
      o0 = __builtin_amdgcn_mfma_f32_16x16x32_bf16(pf.v8, vf0, o0, 0, 0, 0);
      o1 = __builtin_amdgcn_mfma_f32_16x16x32_bf16(pf.v8, vf1, o1, 0, 0, 0);
    }
    l += __shfl_xor(l, 16);
    l += __shfl_xor(l, 32);

    // Epilogue: O rows m=quad*4+r are queries q0+m; l lives at lane c=m.
    // Store into swizzled tile layout: tile (M>>7, kt=h), row M&127,
    // chunk lch ^ ((row>>1)&3) -- proj reads via global_load_lds.
#pragma unroll
    for (int r = 0; r < 4; ++r) {
      int n = q0 + quad * 4 + r;
      if (n < WN) {
        float lq = __shfl(l, quad * 4 + r, 16);
        float inv = 1.0f / lq;
        int M = b * WN + n;
        int rloc = M & 127;
        int xr = (rloc >> 1) & 3;
        size_t base2 = (((size_t)(M >> 7) * 6 + h) << 12) + rloc * 32;
        ob[base2 + (((c >> 3) ^ xr) << 3) + (c & 7)] = f2bf(o0[r] * inv);
        ob[base2 + ((((c >> 3) | 2) ^ xr) << 3) + (c & 7)] = f2bf(o1[r] * inv);
      }
    }
  }
}

// ---------------- output projection (r4): qkv-r3 pattern. 64x192 tile,
// grid 686; obuf (written swizzled by attn) and pre-swizzled wpb staged via
// global_load_lds width-16 (1+3 DMAs per ktile, zero staging VALU); fp32 out.
__global__ __launch_bounds__(256) void proj_kernel(
    const unsigned short* __restrict__ obp, const unsigned short* __restrict__ wpb,
    const float* __restrict__ bvec, float* __restrict__ out) {
  __shared__ __align__(16) unsigned short SL[8192];   // 16KB
  unsigned short* XL = SL;            // 64x32 linear (swizzled chunks)
  unsigned short* WL = SL + 2048;     // 192x32 linear
  const int tid = threadIdx.x;
  const int wave = tid >> 6, lane = tid & 63;
  const int quad = lane >> 4, c = lane & 15;
  const int m0 = blockIdx.x * 64;
  const int mb = blockIdx.x >> 1;
  const int r0 = (blockIdx.x & 1) * 64;
  const int chk = (quad ^ ((c >> 1) & 3)) * 8;

  f32x4 acc[12];
#pragma unroll
  for (int j = 0; j < 12; ++j) acc[j] = (f32x4){0.f, 0.f, 0.f, 0.f};

  for (int kt = 0; kt < 6; ++kt) {
    const unsigned short* gx =
        obp + (((size_t)mb * 6 + kt) << 12) + r0 * 32 + tid * 8;
    const unsigned short* gw = wpb + (size_t)kt * 6144 + tid * 8;
    unsigned short* lx = XL + (size_t)wave * 512;
    unsigned short* lw = WL + (size_t)wave * 512;
    gload16(gx, lx);
    gload16(gw, lw);
    gload16(gw + 2048, lw + 2048);
    gload16(gw + 4096, lw + 4096);
    __syncthreads();
    short8 af = *(const short8*)&XL[(wave * 16 + c) * 32 + chk];
#pragma unroll
    for (int j = 0; j < 12; ++j) {
      short8 bfr = *(const short8*)&WL[(j * 16 + c) * 32 + chk];
      acc[j] = __builtin_amdgcn_mfma_f32_16x16x32_bf16(af, bfr, acc[j], 0, 0, 0);
    }
    __syncthreads();
  }

#pragma unroll
  for (int j = 0; j < 12; ++j) {
    int col = j * 16 + c;
    float bn = bvec[col];
#pragma unroll
    for (int r = 0; r < 4; ++r) {
      int m = m0 + wave * 16 + quad * 4 + r;
      out[(size_t)m * CD + col] = acc[j][r] + bn;
    }
  }
}

extern "C" void kernel_launch(void* const* d_in, const int* in_sizes, int n_in,
                              void* d_out, int out_size, void* d_ws, size_t ws_size,
                              hipStream_t stream) {
  const float* x      = (const float*)d_in[0];
  const float* mask   = (const float*)d_in[1];
  const float* qkv_w  = (const float*)d_in[2];
  const float* qkv_b  = (const float*)d_in[3];
  const float* proj_w = (const float*)d_in[4];
  const float* proj_b = (const float*)d_in[5];
  const float* rpb    = (const float*)d_in[6];
  const int*   rel    = (const int*)d_in[7];
  float* out = (float*)d_out;

  char* ws = (char*)d_ws;
  uint32_t* bmP = (uint32_t*)ws;                          // 192*61952*4 = 47,579,136
  size_t off = 47579136;
  unsigned short* qb = (unsigned short*)(ws + off); off += 16859136;
  unsigned short* kb = (unsigned short*)(ws + off); off += 16859136;
  unsigned short* vb = (unsigned short*)(ws + off); off += 16859136;
  unsigned short* obuf = (unsigned short*)(ws + off); off += 16859136;
  unsigned short* wqb = (unsigned short*)(ws + off); off += 221184;
  unsigned short* wpb = (unsigned short*)(ws + off); off += 73728;
  unsigned short* xb  = (unsigned short*)(ws + off); off += 16859136;

  hipLaunchKernelGGL(prep_kernel, dim3(352 + 54 + 18 + 4116), dim3(256), 0, stream,
                     qkv_w, proj_w, wqb, wpb, rel, rpb, mask, bmP, x, xb);
  hipLaunchKernelGGL(qkv_kernel, dim3(343, 3), dim3(256), 0, stream,
                     xb, wqb, qkv_b, qb, kb, vb);
  hipLaunchKernelGGL(attn_kernel, dim3(NH * NB), dim3(512), 0, stream,
                     qb, kb, vb, bmP, obuf);
  hipLaunchKernelGGL(proj_kernel, dim3(686), dim3(256), 0, stream,
                     obuf, wpb, proj_b, out);
}

// Round 5
// 234.761 us; speedup vs baseline: 1.1112x; 1.1112x over previous
//
#include <hip/hip_runtime.h>
#include <hip/hip_fp16.h>
#include <hip/hip_bf16.h>
#include <stdint.h>

#define WN 343       // tokens per window
#define NH 6         // heads
#define HD 32        // head dim
#define CD 192       // channels
#define NB 128       // windows (batch)
#define NWM 32       // mask windows
#define BMROW 352            // padded query dim
#define BMSLICE (11*16*BMROW) // dwords per slice = 61952
#define BMKC (16*BMROW)       // dwords per kc chunk = 5632
#define LOG2E 1.4426950408889634f

typedef __attribute__((ext_vector_type(8))) short short8;
typedef __attribute__((ext_vector_type(4))) float f32x4;

__device__ __forceinline__ unsigned short f2bf(float f) {
  union { float f; uint32_t u; } v; v.f = f;
  uint32_t r = v.u + 0x7fffu + ((v.u >> 16) & 1u);
  return (unsigned short)(r >> 16);
}

// packed f32x2 -> bf16x2 (v_cvt_pk_bf16_f32 on gfx950); low half = a
__device__ __forceinline__ uint32_t pk2bf(float a, float b) {
  __hip_bfloat162 h = __float22bfloat162_rn(make_float2(a, b));
  return *(uint32_t*)&h;
}

__device__ __forceinline__ uint32_t pkh2(float a, float b) {
  __half2 h; h.x = __float2half(a); h.y = __float2half(b);
  return *(uint32_t*)&h;
}

// async global->LDS, 16B per lane; LDS dest is wave-uniform base + lane*16
typedef const __attribute__((address_space(1))) unsigned int* gas_ptr;
typedef __attribute__((address_space(3))) unsigned int* las_ptr;
__device__ __forceinline__ void gload16(const unsigned short* g, unsigned short* l) {
  __builtin_amdgcn_global_load_lds((gas_ptr)(const void*)g, (las_ptr)(void*)l, 16, 0, 0);
}

// ---------------- prep (r5 = r3 structure): bias repack (66) | mask repack
// (352) | wq swizzle (54) | wp swizzle (18) | x swizzle-cvt (4116).
// bias/mask layout: slice[kc][quad][n][r] f16x2 words, pre-scaled by log2(e);
// OOB bias=-30000 (exp2 -> 0), mask=0. The rpb gather runs ONCE per (h,kc)
// (r4 lesson: recomputing it per-wdx was 24M gathers -> 90us prep).
// Separate bmfuse kernel then sums bias+mask into the per-(wdx,h) buffer.
// wq/wp/x swizzled-tile layout: per 32-k tile, row-major 64B rows, 16B
// chunks permuted cc = lch ^ ((row>>1)&3); consumers stage LINEARLY via
// global_load_lds and read fragments at chunk (quad ^ ((c>>1)&3)).
__global__ __launch_bounds__(256) void prep_kernel(
    const float* __restrict__ wq, const float* __restrict__ wp,
    unsigned short* __restrict__ wqb, unsigned short* __restrict__ wpb,
    const int* __restrict__ rel, const float* __restrict__ rpb,
    const float* __restrict__ mask, uint32_t* __restrict__ bP,
    uint32_t* __restrict__ mP, const float* __restrict__ x,
    unsigned short* __restrict__ xb) {
  __shared__ float M[352][33];
  const int bid = blockIdx.x;
  const int tid = threadIdx.x;
  if (bid < 66 + 352) {
    const bool isBias = (bid < 66);
    const int sub = isBias ? bid : bid - 66;
    const int grp = sub / 11;          // h or wdx
    const int kc = sub - grp * 11;
    const int k0 = kc * 32;
    const float* mw = mask + (size_t)grp * (WN * WN);
    for (int idx = tid; idx < 352 * 32; idx += 256) {
      int n = idx >> 5, k = idx & 31;
      float v;
      if (isBias) {
        int nc = (n < WN) ? n : (WN - 1);
        v = (k0 + k < WN) ? rpb[rel[nc * WN + k0 + k] * NH + grp] * LOG2E
                          : -30000.0f;
      } else {
        v = (n < WN && k0 + k < WN) ? mw[n * WN + k0 + k] * LOG2E : 0.0f;
      }
      M[n][k] = v;
    }
    __syncthreads();
    uint32_t* outp = (isBias ? bP : mP) + (size_t)grp * BMSLICE + (size_t)kc * BMKC;
#pragma unroll
    for (int quad = 0; quad < 4; ++quad) {
#pragma unroll
      for (int j = 0; j < 2; ++j) {
        int n = tid + 256 * j;
        if (n < 352) {
          uint4 o;
          o.x = pkh2(M[n][quad * 8 + 0], M[n][quad * 8 + 4]);
          o.y = pkh2(M[n][quad * 8 + 1], M[n][quad * 8 + 5]);
          o.z = pkh2(M[n][quad * 8 + 2], M[n][quad * 8 + 6]);
          o.w = pkh2(M[n][quad * 8 + 3], M[n][quad * 8 + 7]);
          *(uint4*)(outp + ((size_t)quad * 352 + n) * 4) = o;
        }
      }
    }
    return;
  }
  int cb = bid - 418;
  if (cb < 54) {
    // wq -> swizzled bf16 tiles: 18 tiles (s*6+kt) x 192 rows x 4 chunks
    int g = cb * 256 + tid;            // < 13824
    int sk = g / 768; int rem = g - sk * 768;
    int row = rem >> 2; int cc = rem & 3;
    int s = sk / 6; int kt = sk - s * 6;
    int lch = cc ^ ((row >> 1) & 3);
    const float* src = wq + (size_t)(s * 192 + row) * CD + kt * 32 + lch * 8;
    f32x4 a = *(const f32x4*)src;
    f32x4 b = *(const f32x4*)(src + 4);
    union { short8 v8; uint32_t d[4]; } pk;
    pk.d[0] = pk2bf(a[0], a[1]);
    pk.d[1] = pk2bf(a[2], a[3]);
    pk.d[2] = pk2bf(b[0], b[1]);
    pk.d[3] = pk2bf(b[2], b[3]);
    *(short8*)(wqb + (size_t)g * 8) = pk.v8;
    return;
  }
  cb -= 54;
  if (cb < 18) {
    // wp -> swizzled bf16 tiles: 6 tiles (kt) x 192 rows x 4 chunks
    int g = cb * 256 + tid;            // < 4608
    int kt = g / 768; int rem = g - kt * 768;
    int row = rem >> 2; int cc = rem & 3;
    int lch = cc ^ ((row >> 1) & 3);
    const float* src = wp + (size_t)row * CD + kt * 32 + lch * 8;
    f32x4 a = *(const f32x4*)src;
    f32x4 b = *(const f32x4*)(src + 4);
    union { short8 v8; uint32_t d[4]; } pk;
    pk.d[0] = pk2bf(a[0], a[1]);
    pk.d[1] = pk2bf(a[2], a[3]);
    pk.d[2] = pk2bf(b[0], b[1]);
    pk.d[3] = pk2bf(b[2], b[3]);
    *(short8*)(wpb + (size_t)g * 8) = pk.v8;
    return;
  }
  cb -= 18;
  // x -> swizzled bf16 tiles: 343*6 tiles x 128 rows x 4 chunks
  size_t gx = (size_t)cb * 256 + tid;  // < 1,053,696
  int tile = (int)(gx >> 9); int rem = (int)(gx & 511);
  int row = rem >> 2; int cc = rem & 3;
  int mb = tile / 6; int kt = tile - mb * 6;
  int lch = cc ^ ((row >> 1) & 3);
  const float* src = x + ((size_t)mb * 128 + row) * CD + kt * 32 + lch * 8;
  f32x4 a = *(const f32x4*)src;
  f32x4 b = *(const f32x4*)(src + 4);
  union { short8 v8; uint32_t d[4]; } pk;
  pk.d[0] = pk2bf(a[0], a[1]);
  pk.d[1] = pk2bf(a[2], a[3]);
  pk.d[2] = pk2bf(b[0], b[1]);
  pk.d[3] = pk2bf(b[2], b[3]);
  *(short8*)(xb + gx * 8) = pk.v8;
}

// ---------------- bm fuse (r5): bmP[wdx*6+h] = biasP[h] + maskP[wdx],
// elementwise f16x2 (identical math to r1's in-attn __hadd2). biasP (1.5MB)
// and maskP (7.9MB) are L2-resident with 32x/6x reuse; write 47.6MB ->
// trivially BW-bound streaming add (~10us).
__global__ __launch_bounds__(256) void bmfuse_kernel(
    const uint32_t* __restrict__ bP, const uint32_t* __restrict__ mP,
    uint32_t* __restrict__ bmP) {
  const int slice = blockIdx.y;        // wdx*6 + h
  const int wdx = slice / NH;
  const int h = slice - wdx * NH;
  int i = (blockIdx.x * 256 + threadIdx.x) * 4;
  if (i >= BMSLICE) return;
  uint4 bb = *(const uint4*)(bP + (size_t)h * BMSLICE + i);
  uint4 mm = *(const uint4*)(mP + (size_t)wdx * BMSLICE + i);
  uint4 o; __half2 t;
  t = __hadd2(*(__half2*)&bb.x, *(__half2*)&mm.x); o.x = *(uint32_t*)&t;
  t = __hadd2(*(__half2*)&bb.y, *(__half2*)&mm.y); o.y = *(uint32_t*)&t;
  t = __hadd2(*(__half2*)&bb.z, *(__half2*)&mm.z); o.z = *(uint32_t*)&t;
  t = __hadd2(*(__half2*)&bb.w, *(__half2*)&mm.w); o.w = *(uint32_t*)&t;
  *(uint4*)(bmP + (size_t)slice * BMSLICE + i) = o;
}

// ---------------- QKV GEMM (r3 structure, unchanged): 128x192 tile, 6
// ktiles, 2 barriers each, staging via global_load_lds width-16 from the
// pre-swizzled bf16 xb/wqb. Epilogue repack (stride 36) overlays staging LDS.
__global__ __launch_bounds__(256) void qkv_kernel(
    const unsigned short* __restrict__ xb, const unsigned short* __restrict__ wqb,
    const float* __restrict__ bvec,
    unsigned short* __restrict__ qb, unsigned short* __restrict__ kb,
    unsigned short* __restrict__ vb) {
  __shared__ __align__(16) unsigned short SL[10240];   // 20KB
  unsigned short* XL = SL;            // 128x32 linear (swizzled chunks)
  unsigned short* WL = SL + 4096;     // 192x32 linear
  const int tid = threadIdx.x;
  const int wave = tid >> 6, lane = tid & 63;
  const int quad = lane >> 4, c = lane & 15;
  const int m0 = blockIdx.x * 128;
  const int s = blockIdx.y;            // 0=q, 1=k, 2=v
  const int chk = (quad ^ ((c >> 1) & 3)) * 8;

  f32x4 acc[2][12];
#pragma unroll
  for (int i = 0; i < 2; ++i)
#pragma unroll
    for (int j = 0; j < 12; ++j) acc[i][j] = (f32x4){0.f, 0.f, 0.f, 0.f};

  const size_t xt0 = (size_t)blockIdx.x * 6;
  const size_t wt0 = (size_t)s * 6;
  for (int kt = 0; kt < 6; ++kt) {
    const unsigned short* gx = xb + ((xt0 + kt) << 12) + tid * 8;
    const unsigned short* gw = wqb + (wt0 + kt) * 6144 + tid * 8;
    unsigned short* lx = XL + (size_t)wave * 512;   // wave-uniform, 1KB/wave
    unsigned short* lw = WL + (size_t)wave * 512;
    gload16(gx, lx);
    gload16(gx + 2048, lx + 2048);
    gload16(gw, lw);
    gload16(gw + 2048, lw + 2048);
    gload16(gw + 4096, lw + 4096);
    __syncthreads();
    short8 af0 = *(const short8*)&XL[(wave * 32 + c) * 32 + chk];
    short8 af1 = *(const short8*)&XL[(wave * 32 + 16 + c) * 32 + chk];
#pragma unroll
    for (int j = 0; j < 12; ++j) {
      short8 bfr = *(const short8*)&WL[(j * 16 + c) * 32 + chk];
      acc[0][j] = __builtin_amdgcn_mfma_f32_16x16x32_bf16(af0, bfr, acc[0][j], 0, 0, 0);
      acc[1][j] = __builtin_amdgcn_mfma_f32_16x16x32_bf16(af1, bfr, acc[1][j], 0, 0, 0);
    }
    __syncthreads();
  }

  // q scale folded with log2(e): 32^-0.5 * 1.4426950409 (softmax runs in
  // exp2 domain; bm pre-scaled by log2(e) in prep)
  const float qscale = 0.25503486f;
  unsigned short* dst = (s == 0) ? qb : ((s == 1) ? kb : vb);
  const float scl = (s == 0) ? qscale : 1.0f;
  const int n0 = s * 192;
  // repack overlays dead staging LDS; stride 36 shorts -> all-32-bank writes
  unsigned short* Lh0 = SL;            // 128 rows x 36
  unsigned short* Lh1 = SL + 4608;
  for (int hh = 0; hh < 3; ++hh) {
    __syncthreads();
#pragma unroll
    for (int jj = 0; jj < 4; ++jj) {
      int j = hh * 4 + jj;
      int hl = jj >> 1;
      int dd = (jj & 1) * 16 + c;
      float bn = bvec[n0 + j * 16 + c];
      unsigned short* L = hl ? Lh1 : Lh0;
#pragma unroll
      for (int i = 0; i < 2; ++i)
#pragma unroll
        for (int r = 0; r < 4; ++r) {
          int m = wave * 32 + i * 16 + quad * 4 + r;
          L[m * 36 + dd] = f2bf((acc[i][j][r] + bn) * scl);
        }
    }
    __syncthreads();
    const int m = tid & 127;
    const int hl = tid >> 7;
    const int M = m0 + m;
    const int b = M / WN;
    const int tok = M - b * WN;
    const int h = hh * 2 + hl;
    const unsigned short* L = hl ? Lh1 : Lh0;
    unsigned short* drow = dst + (((size_t)b * NH + h) * WN + tok) * HD;
#pragma unroll
    for (int t2 = 0; t2 < 4; ++t2) {
      int d0 = t2 * 8;
      *(short8*)&drow[d0] = *(const short8*)&L[m * 36 + d0];
    }
  }
}

// ---------------- fused attention (r4 structure, unchanged): single
// streaming loop, no max-sub. 512 threads (8 waves); LDS 51KB. XCD-aware
// remap: 24 blocks sharing one mask slice land on the SAME XCD. Per kc the
// C-operand is ONE dwordx4 from the fused bm buffer. O stored in the
// swizzled tile layout proj stages with global_load_lds (kt == head).
// NOTE: plain __launch_bounds__ — a min-waves arg makes the allocator cap
// VGPRs and spill (r5: +29MB).
__global__ __launch_bounds__(512) void attn_kernel(
    const unsigned short* __restrict__ qb, const unsigned short* __restrict__ kb,
    const unsigned short* __restrict__ vb, const uint32_t* __restrict__ bmP,
    unsigned short* __restrict__ ob) {
  __shared__ __align__(16) unsigned short Ks[352][40];  // [perm key row][d]
  __shared__ __align__(16) unsigned short Vt[HD][360];  // [d][key]
  // XCD swizzle: bid%8 = XCD (observed round-robin); job groups of 24 share wdx
  const int bid = blockIdx.x;
  const int job = (bid & 7) * 96 + (bid >> 3);
  const int wdx = job / 24;
  const int inner = job - wdx * 24;
  const int h = inner >> 2;
  const int b = (inner & 3) * 32 + wdx;   // preserves wdx == b & 31
  const int tid = threadIdx.x;
  const int wave = tid >> 6, lane = tid & 63;
  const int quad = lane >> 4, c = lane & 15;
  const size_t base = ((size_t)b * NH + h) * (WN * HD);
  const unsigned short* q = qb + base;
  const unsigned short* k = kb + base;
  const unsigned short* v = vb + base;
  const uint32_t* bmS = bmP + (size_t)(wdx * 6 + h) * BMSLICE;

  // stage K with permuted rows
  for (int t = tid; t < WN * 4; t += 512) {
    int r = t >> 2, ch = t & 3;
    int kk = r & 31;
    int row = (r & ~31) + 16 * ((kk >> 2) & 1) + 4 * (kk >> 3) + (kk & 3);
    *(short8*)&Ks[row][ch * 8] = *(const short8*)(k + r * HD + ch * 8);
  }
  for (int t = tid; t < 9 * 32; t += 512) {
    int kg = WN + (t >> 5);
    int kk = kg & 31;
    int row = (kg & ~31) + 16 * ((kk >> 2) & 1) + 4 * (kk >> 3) + (kk & 3);
    Ks[row][t & 31] = 0;
  }
  // stage V transposed, natural key order
  for (int t = tid; t < WN; t += 512) {
#pragma unroll
    for (int ch = 0; ch < 4; ++ch) {
      short8 vv = *(const short8*)(v + t * HD + ch * 8);
#pragma unroll
      for (int j = 0; j < 8; ++j) Vt[ch * 8 + j][t] = vv[j];
    }
  }
  for (int t = tid; t < 9 * 32; t += 512) {
    Vt[t & 31][WN + (t >> 5)] = 0;
  }
  __syncthreads();

  for (int qt = wave; qt < 22; qt += 8) {
    const int q0 = qt * 16;
    int qr = q0 + c; if (qr > WN - 1) qr = WN - 1;
    const short8 qf = *(const short8*)(q + qr * HD + quad * 8);
    const uint32_t* bmRow = bmS + ((size_t)quad * 352 + q0 + c) * 4;

    f32x4 o0 = (f32x4){0.f, 0.f, 0.f, 0.f}, o1 = (f32x4){0.f, 0.f, 0.f, 0.f};
    float l = 0.f;
#pragma unroll
    for (int kc = 0; kc < 11; ++kc) {
      // C-operand = log2e*(bias+mask) for this lane's 8 keys: ONE dwordx4
      uint4 w4 = *(const uint4*)(bmRow + (size_t)kc * BMKC);
      f32x4 cc0, cc1;
      {
        float2 f;
        f = __half22float2(*(__half2*)&w4.x); cc0[0] = f.x; cc1[0] = f.y;
        f = __half22float2(*(__half2*)&w4.y); cc0[1] = f.x; cc1[1] = f.y;
        f = __half22float2(*(__half2*)&w4.z); cc0[2] = f.x; cc1[2] = f.y;
        f = __half22float2(*(__half2*)&w4.w); cc0[3] = f.x; cc1[3] = f.y;
      }
      const int k0 = kc * 32;
      short8 kf0 = *(const short8*)&Ks[k0 + c][quad * 8];
      short8 kf1 = *(const short8*)&Ks[k0 + 16 + c][quad * 8];
      f32x4 s0 = __builtin_amdgcn_mfma_f32_16x16x32_bf16(kf0, qf, cc0, 0, 0, 0);
      f32x4 s1 = __builtin_amdgcn_mfma_f32_16x16x32_bf16(kf1, qf, cc1, 0, 0, 0);
      // scores are in log2 domain -> direct v_exp_f32 (2^x), unnormalized;
      // OOB keys carry -30000 -> exp2==0
      float p0 = __builtin_amdgcn_exp2f(s0[0]), p1 = __builtin_amdgcn_exp2f(s0[1]);
      float p2 = __builtin_amdgcn_exp2f(s0[2]), p3 = __builtin_amdgcn_exp2f(s0[3]);
      float p4 = __builtin_amdgcn_exp2f(s1[0]), p5 = __builtin_amdgcn_exp2f(s1[1]);
      float p6 = __builtin_amdgcn_exp2f(s1[2]), p7 = __builtin_amdgcn_exp2f(s1[3]);
      l += (p0 + p1 + p2 + p3) + (p4 + p5 + p6 + p7);
      union { short8 v8; uint32_t d[4]; } pf;
      pf.d[0] = pk2bf(p0, p1);
      pf.d[1] = pk2bf(p2, p3);
      pf.d[2] = pk2bf(p4, p5);
      pf.d[3] = pk2bf(p6, p7);
      short8 vf0 = *(const short8*)&Vt[c][k0 + quad * 8];
      short8 vf1 = *(const short8*)&Vt[16 + c][k0 + quad * 8];
      o0 = __builtin_amdgcn_mfma_f32_16x16x32_bf16(pf.v8, vf0, o0, 0, 0, 0);
      o1 = __builtin_amdgcn_mfma_f32_16x16x32_bf16(pf.v8, vf1, o1, 0, 0, 0);
    }
    l += __shfl_xor(l, 16);
    l += __shfl_xor(l, 32);

    // Epilogue: O rows m=quad*4+r are queries q0+m; l lives at lane c=m.
    // Store into swizzled tile layout: tile (M>>7, kt=h), row M&127,
    // chunk lch ^ ((row>>1)&3) -- proj reads via global_load_lds.
#pragma unroll
    for (int r = 0; r < 4; ++r) {
      int n = q0 + quad * 4 + r;
      if (n < WN) {
        float lq = __shfl(l, quad * 4 + r, 16);
        float inv = 1.0f / lq;
        int M = b * WN + n;
        int rloc = M & 127;
        int xr = (rloc >> 1) & 3;
        size_t base2 = (((size_t)(M >> 7) * 6 + h) << 12) + rloc * 32;
        ob[base2 + (((c >> 3) ^ xr) << 3) + (c & 7)] = f2bf(o0[r] * inv);
        ob[base2 + ((((c >> 3) | 2) ^ xr) << 3) + (c & 7)] = f2bf(o1[r] * inv);
      }
    }
  }
}

// ---------------- output projection (r4 structure, unchanged): 64x192 tile,
// grid 686; obuf (written swizzled by attn) and pre-swizzled wpb staged via
// global_load_lds width-16 (1+3 DMAs per ktile, zero staging VALU); fp32 out.
__global__ __launch_bounds__(256) void proj_kernel(
    const unsigned short* __restrict__ obp, const unsigned short* __restrict__ wpb,
    const float* __restrict__ bvec, float* __restrict__ out) {
  __shared__ __align__(16) unsigned short SL[8192];   // 16KB
  unsigned short* XL = SL;            // 64x32 linear (swizzled chunks)
  unsigned short* WL = SL + 2048;     // 192x32 linear
  const int tid = threadIdx.x;
  const int wave = tid >> 6, lane = tid & 63;
  const int quad = lane >> 4, c = lane & 15;
  const int m0 = blockIdx.x * 64;
  const int mb = blockIdx.x >> 1;
  const int r0 = (blockIdx.x & 1) * 64;
  const int chk = (quad ^ ((c >> 1) & 3)) * 8;

  f32x4 acc[12];
#pragma unroll
  for (int j = 0; j < 12; ++j) acc[j] = (f32x4){0.f, 0.f, 0.f, 0.f};

  for (int kt = 0; kt < 6; ++kt) {
    const unsigned short* gx =
        obp + (((size_t)mb * 6 + kt) << 12) + r0 * 32 + tid * 8;
    const unsigned short* gw = wpb + (size_t)kt * 6144 + tid * 8;
    unsigned short* lx = XL + (size_t)wave * 512;
    unsigned short* lw = WL + (size_t)wave * 512;
    gload16(gx, lx);
    gload16(gw, lw);
    gload16(gw + 2048, lw + 2048);
    gload16(gw + 4096, lw + 4096);
    __syncthreads();
    short8 af = *(const short8*)&XL[(wave * 16 + c) * 32 + chk];
#pragma unroll
    for (int j = 0; j < 12; ++j) {
      short8 bfr = *(const short8*)&WL[(j * 16 + c) * 32 + chk];
      acc[j] = __builtin_amdgcn_mfma_f32_16x16x32_bf16(af, bfr, acc[j], 0, 0, 0);
    }
    __syncthreads();
  }

#pragma unroll
  for (int j = 0; j < 12; ++j) {
    int col = j * 16 + c;
    float bn = bvec[col];
#pragma unroll
    for (int r = 0; r < 4; ++r) {
      int m = m0 + wave * 16 + quad * 4 + r;
      out[(size_t)m * CD + col] = acc[j][r] + bn;
    }
  }
}

extern "C" void kernel_launch(void* const* d_in, const int* in_sizes, int n_in,
                              void* d_out, int out_size, void* d_ws, size_t ws_size,
                              hipStream_t stream) {
  const float* x      = (const float*)d_in[0];
  const float* mask   = (const float*)d_in[1];
  const float* qkv_w  = (const float*)d_in[2];
  const float* qkv_b  = (const float*)d_in[3];
  const float* proj_w = (const float*)d_in[4];
  const float* proj_b = (const float*)d_in[5];
  const float* rpb    = (const float*)d_in[6];
  const int*   rel    = (const int*)d_in[7];
  float* out = (float*)d_out;

  char* ws = (char*)d_ws;
  uint32_t* biasP = (uint32_t*)ws;                       // 6*61952*4 = 1,486,848
  size_t off = 1486848;
  uint32_t* maskP = (uint32_t*)(ws + off); off += 7929856;   // 32*61952*4
  uint32_t* bmP   = (uint32_t*)(ws + off); off += 47579136;  // 192*61952*4
  unsigned short* qb = (unsigned short*)(ws + off); off += 16859136;
  unsigned short* kb = (unsigned short*)(ws + off); off += 16859136;
  unsigned short* vb = (unsigned short*)(ws + off); off += 16859136;
  unsigned short* wqb = (unsigned short*)(ws + off); off += 221184;
  unsigned short* wpb = (unsigned short*)(ws + off); off += 73728;
  unsigned short* xb  = (unsigned short*)(ws + off); off += 16859136;
  // obuf aliases xb: qkv finishes reading xb before attn writes it
  // (stream-ordered); prep rewrites xb each replay iteration.
  unsigned short* obuf = xb;

  hipLaunchKernelGGL(prep_kernel, dim3(418 + 54 + 18 + 4116), dim3(256), 0, stream,
                     qkv_w, proj_w, wqb, wpb, rel, rpb, mask, biasP, maskP, x, xb);
  hipLaunchKernelGGL(bmfuse_kernel, dim3(61, 192), dim3(256), 0, stream,
                     biasP, maskP, bmP);
  hipLaunchKernelGGL(qkv_kernel, dim3(343, 3), dim3(256), 0, stream,
                     xb, wqb, qkv_b, qb, kb, vb);
  hipLaunchKernelGGL(attn_kernel, dim3(NH * NB), dim3(512), 0, stream,
                     qb, kb, vb, bmP, obuf);
  hipLaunchKernelGGL(proj_kernel, dim3(686), dim3(256), 0, stream,
                     obuf, wpb, proj_b, out);
}

// Round 6
// 219.598 us; speedup vs baseline: 1.1879x; 1.0691x over previous
//
#include <hip/hip_runtime.h>
#include <hip/hip_fp16.h>
#include <hip/hip_bf16.h>
#include <stdint.h>

#define WN 343       // tokens per window
#define NH 6         // heads
#define HD 32        // head dim
#define CD 192       // channels
#define NB 128       // windows (batch)
#define NWM 32       // mask windows
#define BMROW 352            // padded query dim
#define BMSLICE (11*16*BMROW) // dwords per slice = 61952
#define BMKC (16*BMROW)       // dwords per kc chunk = 5632
#define LOG2E 1.4426950408889634f

typedef __attribute__((ext_vector_type(8))) short short8;
typedef __attribute__((ext_vector_type(4))) float f32x4;

__device__ __forceinline__ unsigned short f2bf(float f) {
  union { float f; uint32_t u; } v; v.f = f;
  uint32_t r = v.u + 0x7fffu + ((v.u >> 16) & 1u);
  return (unsigned short)(r >> 16);
}

// packed f32x2 -> bf16x2 (v_cvt_pk_bf16_f32 on gfx950); low half = a
__device__ __forceinline__ uint32_t pk2bf(float a, float b) {
  __hip_bfloat162 h = __float22bfloat162_rn(make_float2(a, b));
  return *(uint32_t*)&h;
}

__device__ __forceinline__ uint32_t pkh2(float a, float b) {
  __half2 h; h.x = __float2half(a); h.y = __float2half(b);
  return *(uint32_t*)&h;
}

// async global->LDS, 16B per lane; LDS dest is wave-uniform base + lane*16
typedef const __attribute__((address_space(1))) unsigned int* gas_ptr;
typedef __attribute__((address_space(3))) unsigned int* las_ptr;
__device__ __forceinline__ void gload16(const unsigned short* g, unsigned short* l) {
  __builtin_amdgcn_global_load_lds((gas_ptr)(const void*)g, (las_ptr)(void*)l, 16, 0, 0);
}

// ---------------- prep_bm: bias repack (264 = 66 pairs x 4 row-groups) |
// mask repack (352). Separate kernel so its 46KB LDS doesn't cap the
// LDS-free cvt branches' occupancy (r5 lesson). Bias gather widened 4x:
// each (h,kc) split into 4 row-groups of 88 -> 264 concurrent blocks
// instead of 66 (the serial rel->rpb gather chain was the latency floor).
// Layout: slice[kc][quad][n][r] f16x2 words, pre-scaled by log2(e);
// OOB keys: bias=-30000 (exp2 -> 0), mask=0. attn sums the two at use
// (both buffers are L2-resident; r5 lesson: materializing the 47.6MB sum
// spilled L2 and cost a full extra streaming pass).
__global__ __launch_bounds__(256) void prep_bm_kernel(
    const int* __restrict__ rel, const float* __restrict__ rpb,
    const float* __restrict__ mask, uint32_t* __restrict__ bP,
    uint32_t* __restrict__ mP) {
  __shared__ float M[352][33];
  const int bid = blockIdx.x;
  const int tid = threadIdx.x;
  if (bid < 264) {
    const int h = bid / 44;
    const int rem = bid - h * 44;
    const int kc = rem >> 2;
    const int g = rem & 3;
    const int n0 = g * 88;
    const int k0 = kc * 32;
    for (int idx = tid; idx < 88 * 32; idx += 256) {
      int nl = idx >> 5, k = idx & 31;
      int n = n0 + nl;
      int nc = (n < WN) ? n : (WN - 1);
      M[nl][k] = (k0 + k < WN) ? rpb[rel[nc * WN + k0 + k] * NH + h] * LOG2E
                               : -30000.0f;
    }
    __syncthreads();
    uint32_t* outp = bP + (size_t)h * BMSLICE + (size_t)kc * BMKC;
    if (tid < 88) {
      const int nl = tid;
      const int n = n0 + nl;
#pragma unroll
      for (int quad = 0; quad < 4; ++quad) {
        uint4 o;
        o.x = pkh2(M[nl][quad * 8 + 0], M[nl][quad * 8 + 4]);
        o.y = pkh2(M[nl][quad * 8 + 1], M[nl][quad * 8 + 5]);
        o.z = pkh2(M[nl][quad * 8 + 2], M[nl][quad * 8 + 6]);
        o.w = pkh2(M[nl][quad * 8 + 3], M[nl][quad * 8 + 7]);
        *(uint4*)(outp + ((size_t)quad * 352 + n) * 4) = o;
      }
    }
    return;
  }
  // mask branch
  const int sub = bid - 264;
  const int wdx = sub / 11;
  const int kc = sub - wdx * 11;
  const int k0 = kc * 32;
  const float* mw = mask + (size_t)wdx * (WN * WN);
  for (int idx = tid; idx < 352 * 32; idx += 256) {
    int n = idx >> 5, k = idx & 31;
    M[n][k] = (n < WN && k0 + k < WN) ? mw[n * WN + k0 + k] * LOG2E : 0.0f;
  }
  __syncthreads();
  uint32_t* outp = mP + (size_t)wdx * BMSLICE + (size_t)kc * BMKC;
#pragma unroll
  for (int quad = 0; quad < 4; ++quad) {
#pragma unroll
    for (int j = 0; j < 2; ++j) {
      int n = tid + 256 * j;
      if (n < 352) {
        uint4 o;
        o.x = pkh2(M[n][quad * 8 + 0], M[n][quad * 8 + 4]);
        o.y = pkh2(M[n][quad * 8 + 1], M[n][quad * 8 + 5]);
        o.z = pkh2(M[n][quad * 8 + 2], M[n][quad * 8 + 6]);
        o.w = pkh2(M[n][quad * 8 + 3], M[n][quad * 8 + 7]);
        *(uint4*)(outp + ((size_t)quad * 352 + n) * 4) = o;
      }
    }
  }
}

// ---------------- prep_cvt: wq swizzle (54) | wp swizzle (18) | x
// swizzle-cvt (4116). LDS-free -> full occupancy streaming.
// Swizzled-tile layout: per 32-k tile, row-major 64B rows, 16B chunks
// permuted cc = lch ^ ((row>>1)&3); consumers stage LINEARLY via
// global_load_lds and read fragments at chunk (quad ^ ((c>>1)&3)).
__global__ __launch_bounds__(256) void prep_cvt_kernel(
    const float* __restrict__ wq, const float* __restrict__ wp,
    const float* __restrict__ x, unsigned short* __restrict__ wqb,
    unsigned short* __restrict__ wpb, unsigned short* __restrict__ xb) {
  const int tid = threadIdx.x;
  int cb = blockIdx.x;
  if (cb < 54) {
    // wq -> swizzled bf16 tiles: 18 tiles (s*6+kt) x 192 rows x 4 chunks
    int g = cb * 256 + tid;            // < 13824
    int sk = g / 768; int rem = g - sk * 768;
    int row = rem >> 2; int cc = rem & 3;
    int s = sk / 6; int kt = sk - s * 6;
    int lch = cc ^ ((row >> 1) & 3);
    const float* src = wq + (size_t)(s * 192 + row) * CD + kt * 32 + lch * 8;
    f32x4 a = *(const f32x4*)src;
    f32x4 b = *(const f32x4*)(src + 4);
    union { short8 v8; uint32_t d[4]; } pk;
    pk.d[0] = pk2bf(a[0], a[1]);
    pk.d[1] = pk2bf(a[2], a[3]);
    pk.d[2] = pk2bf(b[0], b[1]);
    pk.d[3] = pk2bf(b[2], b[3]);
    *(short8*)(wqb + (size_t)g * 8) = pk.v8;
    return;
  }
  cb -= 54;
  if (cb < 18) {
    // wp -> swizzled bf16 tiles: 6 tiles (kt) x 192 rows x 4 chunks
    int g = cb * 256 + tid;            // < 4608
    int kt = g / 768; int rem = g - kt * 768;
    int row = rem >> 2; int cc = rem & 3;
    int lch = cc ^ ((row >> 1) & 3);
    const float* src = wp + (size_t)row * CD + kt * 32 + lch * 8;
    f32x4 a = *(const f32x4*)src;
    f32x4 b = *(const f32x4*)(src + 4);
    union { short8 v8; uint32_t d[4]; } pk;
    pk.d[0] = pk2bf(a[0], a[1]);
    pk.d[1] = pk2bf(a[2], a[3]);
    pk.d[2] = pk2bf(b[0], b[1]);
    pk.d[3] = pk2bf(b[2], b[3]);
    *(short8*)(wpb + (size_t)g * 8) = pk.v8;
    return;
  }
  cb -= 18;
  // x -> swizzled bf16 tiles: 343*6 tiles x 128 rows x 4 chunks
  size_t gx = (size_t)cb * 256 + tid;  // < 1,053,696
  int tile = (int)(gx >> 9); int rem = (int)(gx & 511);
  int row = rem >> 2; int cc = rem & 3;
  int mb = tile / 6; int kt = tile - mb * 6;
  int lch = cc ^ ((row >> 1) & 3);
  const float* src = x + ((size_t)mb * 128 + row) * CD + kt * 32 + lch * 8;
  f32x4 a = *(const f32x4*)src;
  f32x4 b = *(const f32x4*)(src + 4);
  union { short8 v8; uint32_t d[4]; } pk;
  pk.d[0] = pk2bf(a[0], a[1]);
  pk.d[1] = pk2bf(a[2], a[3]);
  pk.d[2] = pk2bf(b[0], b[1]);
  pk.d[3] = pk2bf(b[2], b[3]);
  *(short8*)(xb + gx * 8) = pk.v8;
}

// ---------------- QKV GEMM (r3 structure, unchanged): 128x192 tile, 6
// ktiles, 2 barriers each, staging via global_load_lds width-16 from the
// pre-swizzled bf16 xb/wqb. Epilogue repack (stride 36) overlays staging LDS.
__global__ __launch_bounds__(256) void qkv_kernel(
    const unsigned short* __restrict__ xb, const unsigned short* __restrict__ wqb,
    const float* __restrict__ bvec,
    unsigned short* __restrict__ qb, unsigned short* __restrict__ kb,
    unsigned short* __restrict__ vb) {
  __shared__ __align__(16) unsigned short SL[10240];   // 20KB
  unsigned short* XL = SL;            // 128x32 linear (swizzled chunks)
  unsigned short* WL = SL + 4096;     // 192x32 linear
  const int tid = threadIdx.x;
  const int wave = tid >> 6, lane = tid & 63;
  const int quad = lane >> 4, c = lane & 15;
  const int m0 = blockIdx.x * 128;
  const int s = blockIdx.y;            // 0=q, 1=k, 2=v
  const int chk = (quad ^ ((c >> 1) & 3)) * 8;

  f32x4 acc[2][12];
#pragma unroll
  for (int i = 0; i < 2; ++i)
#pragma unroll
    for (int j = 0; j < 12; ++j) acc[i][j] = (f32x4){0.f, 0.f, 0.f, 0.f};

  const size_t xt0 = (size_t)blockIdx.x * 6;
  const size_t wt0 = (size_t)s * 6;
  for (int kt = 0; kt < 6; ++kt) {
    const unsigned short* gx = xb + ((xt0 + kt) << 12) + tid * 8;
    const unsigned short* gw = wqb + (wt0 + kt) * 6144 + tid * 8;
    unsigned short* lx = XL + (size_t)wave * 512;   // wave-uniform, 1KB/wave
    unsigned short* lw = WL + (size_t)wave * 512;
    gload16(gx, lx);
    gload16(gx + 2048, lx + 2048);
    gload16(gw, lw);
    gload16(gw + 2048, lw + 2048);
    gload16(gw + 4096, lw + 4096);
    __syncthreads();
    short8 af0 = *(const short8*)&XL[(wave * 32 + c) * 32 + chk];
    short8 af1 = *(const short8*)&XL[(wave * 32 + 16 + c) * 32 + chk];
#pragma unroll
    for (int j = 0; j < 12; ++j) {
      short8 bfr = *(const short8*)&WL[(j * 16 + c) * 32 + chk];
      acc[0][j] = __builtin_amdgcn_mfma_f32_16x16x32_bf16(af0, bfr, acc[0][j], 0, 0, 0);
      acc[1][j] = __builtin_amdgcn_mfma_f32_16x16x32_bf16(af1, bfr, acc[1][j], 0, 0, 0);
    }
    __syncthreads();
  }

  // q scale folded with log2(e): 32^-0.5 * 1.4426950409 (softmax runs in
  // exp2 domain; bias/mask pre-scaled by log2(e) in prep)
  const float qscale = 0.25503486f;
  unsigned short* dst = (s == 0) ? qb : ((s == 1) ? kb : vb);
  const float scl = (s == 0) ? qscale : 1.0f;
  const int n0 = s * 192;
  // repack overlays dead staging LDS; stride 36 shorts -> all-32-bank writes
  unsigned short* Lh0 = SL;            // 128 rows x 36
  unsigned short* Lh1 = SL + 4608;
  for (int hh = 0; hh < 3; ++hh) {
    __syncthreads();
#pragma unroll
    for (int jj = 0; jj < 4; ++jj) {
      int j = hh * 4 + jj;
      int hl = jj >> 1;
      int dd = (jj & 1) * 16 + c;
      float bn = bvec[n0 + j * 16 + c];
      unsigned short* L = hl ? Lh1 : Lh0;
#pragma unroll
      for (int i = 0; i < 2; ++i)
#pragma unroll
        for (int r = 0; r < 4; ++r) {
          int m = wave * 32 + i * 16 + quad * 4 + r;
          L[m * 36 + dd] = f2bf((acc[i][j][r] + bn) * scl);
        }
    }
    __syncthreads();
    const int m = tid & 127;
    const int hl = tid >> 7;
    const int M = m0 + m;
    const int b = M / WN;
    const int tok = M - b * WN;
    const int h = hh * 2 + hl;
    const unsigned short* L = hl ? Lh1 : Lh0;
    unsigned short* drow = dst + (((size_t)b * NH + h) * WN + tok) * HD;
#pragma unroll
    for (int t2 = 0; t2 < 4; ++t2) {
      int d0 = t2 * 8;
      *(short8*)&drow[d0] = *(const short8*)&L[m * 36 + d0];
    }
  }
}

// ---------------- fused attention (r6): two C-operand loads per kc (bias
// 1.5MB + mask 7.9MB, both L2-resident with XCD clustering -- r5 lesson:
// the materialized 47.6MB sum spilled L2). kc loop unroll-2 (was full):
// drops ~72 VGPRs of hoisted loads, targeting <=84 VGPR -> 6 waves/SIMD ->
// 3 blocks/CU -> all 768 blocks resident in ONE round (at 2/CU the grid
// ran 512+256 = 25% avg idle). NOTE: plain __launch_bounds__ — a min-waves
// arg makes the allocator cap VGPRs and spill (r5: +29MB).
__global__ __launch_bounds__(512) void attn_kernel(
    const unsigned short* __restrict__ qb, const unsigned short* __restrict__ kb,
    const unsigned short* __restrict__ vb, const uint32_t* __restrict__ biasP,
    const uint32_t* __restrict__ maskP, unsigned short* __restrict__ ob) {
  __shared__ __align__(16) unsigned short Ks[352][40];  // [perm key row][d]
  __shared__ __align__(16) unsigned short Vt[HD][360];  // [d][key]
  // XCD swizzle: bid%8 = XCD (observed round-robin); job groups of 24 share wdx
  const int bid = blockIdx.x;
  const int job = (bid & 7) * 96 + (bid >> 3);
  const int wdx = job / 24;
  const int inner = job - wdx * 24;
  const int h = inner >> 2;
  const int b = (inner & 3) * 32 + wdx;   // preserves wdx == b & 31
  const int tid = threadIdx.x;
  const int wave = tid >> 6, lane = tid & 63;
  const int quad = lane >> 4, c = lane & 15;
  const size_t base = ((size_t)b * NH + h) * (WN * HD);
  const unsigned short* q = qb + base;
  const unsigned short* k = kb + base;
  const unsigned short* v = vb + base;
  const uint32_t* bS = biasP + (size_t)h * BMSLICE;
  const uint32_t* mS = maskP + (size_t)wdx * BMSLICE;

  // stage K with permuted rows
  for (int t = tid; t < WN * 4; t += 512) {
    int r = t >> 2, ch = t & 3;
    int kk = r & 31;
    int row = (r & ~31) + 16 * ((kk >> 2) & 1) + 4 * (kk >> 3) + (kk & 3);
    *(short8*)&Ks[row][ch * 8] = *(const short8*)(k + r * HD + ch * 8);
  }
  for (int t = tid; t < 9 * 32; t += 512) {
    int kg = WN + (t >> 5);
    int kk = kg & 31;
    int row = (kg & ~31) + 16 * ((kk >> 2) & 1) + 4 * (kk >> 3) + (kk & 3);
    Ks[row][t & 31] = 0;
  }
  // stage V transposed, natural key order
  for (int t = tid; t < WN; t += 512) {
#pragma unroll
    for (int ch = 0; ch < 4; ++ch) {
      short8 vv = *(const short8*)(v + t * HD + ch * 8);
#pragma unroll
      for (int j = 0; j < 8; ++j) Vt[ch * 8 + j][t] = vv[j];
    }
  }
  for (int t = tid; t < 9 * 32; t += 512) {
    Vt[t & 31][WN + (t >> 5)] = 0;
  }
  __syncthreads();

  for (int qt = wave; qt < 22; qt += 8) {
    const int q0 = qt * 16;
    int qr = q0 + c; if (qr > WN - 1) qr = WN - 1;
    const short8 qf = *(const short8*)(q + qr * HD + quad * 8);
    const uint32_t* bRow = bS + ((size_t)quad * 352 + q0 + c) * 4;
    const uint32_t* mRow = mS + ((size_t)quad * 352 + q0 + c) * 4;

    f32x4 o0 = (f32x4){0.f, 0.f, 0.f, 0.f}, o1 = (f32x4){0.f, 0.f, 0.f, 0.f};
    float l = 0.f;
#pragma unroll 2
    for (int kc = 0; kc < 11; ++kc) {
      // C-operand = log2e*(bias+mask) for this lane's 8 keys: 2x dwordx4
      uint4 bw4 = *(const uint4*)(bRow + (size_t)kc * BMKC);
      uint4 mw4 = *(const uint4*)(mRow + (size_t)kc * BMKC);
      f32x4 cc0, cc1;
      {
        __half2 s2; float2 f;
        s2 = __hadd2(*(__half2*)&bw4.x, *(__half2*)&mw4.x);
        f = __half22float2(s2); cc0[0] = f.x; cc1[0] = f.y;
        s2 = __hadd2(*(__half2*)&bw4.y, *(__half2*)&mw4.y);
        f = __half22float2(s2); cc0[1] = f.x; cc1[1] = f.y;
        s2 = __hadd2(*(__half2*)&bw4.z, *(__half2*)&mw4.z);
        f = __half22float2(s2); cc0[2] = f.x; cc1[2] = f.y;
        s2 = __hadd2(*(__half2*)&bw4.w, *(__half2*)&mw4.w);
        f = __half22float2(s2); cc0[3] = f.x; cc1[3] = f.y;
      }
      const int k0 = kc * 32;
      short8 kf0 = *(const short8*)&Ks[k0 + c][quad * 8];
      short8 kf1 = *(const short8*)&Ks[k0 + 16 + c][quad * 8];
      f32x4 s0 = __builtin_amdgcn_mfma_f32_16x16x32_bf16(kf0, qf, cc0, 0, 0, 0);
      f32x4 s1 = __builtin_amdgcn_mfma_f32_16x16x32_bf16(kf1, qf, cc1, 0, 0, 0);
      // scores are in log2 domain -> direct v_exp_f32 (2^x), unnormalized;
      // OOB keys carry -30000 -> exp2==0
      float p0 = __builtin_amdgcn_exp2f(s0[0]), p1 = __builtin_amdgcn_exp2f(s0[1]);
      float p2 = __builtin_amdgcn_exp2f(s0[2]), p3 = __builtin_amdgcn_exp2f(s0[3]);
      float p4 = __builtin_amdgcn_exp2f(s1[0]), p5 = __builtin_amdgcn_exp2f(s1[1]);
      float p6 = __builtin_amdgcn_exp2f(s1[2]), p7 = __builtin_amdgcn_exp2f(s1[3]);
      l += (p0 + p1 + p2 + p3) + (p4 + p5 + p6 + p7);
      union { short8 v8; uint32_t d[4]; } pf;
      pf.d[0] = pk2bf(p0, p1);
      pf.d[1] = pk2bf(p2, p3);
      pf.d[2] = pk2bf(p4, p5);
      pf.d[3] = pk2bf(p6, p7);
      short8 vf0 = *(const short8*)&Vt[c][k0 + quad * 8];
      short8 vf1 = *(const short8*)&Vt[16 + c][k0 + quad * 8];
      o0 = __builtin_amdgcn_mfma_f32_16x16x32_bf16(pf.v8, vf0, o0, 0, 0, 0);
      o1 = __builtin_amdgcn_mfma_f32_16x16x32_bf16(pf.v8, vf1, o1, 0, 0, 0);
    }
    l += __shfl_xor(l, 16);
    l += __shfl_xor(l, 32);

    // Epilogue: O rows m=quad*4+r are queries q0+m; l lives at lane c=m.
    // Store into swizzled tile layout: tile (M>>7, kt=h), row M&127,
    // chunk lch ^ ((row>>1)&3) -- proj reads via global_load_lds.
#pragma unroll
    for (int r = 0; r < 4; ++r) {
      int n = q0 + quad * 4 + r;
      if (n < WN) {
        float lq = __shfl(l, quad * 4 + r, 16);
        float inv = 1.0f / lq;
        int M = b * WN + n;
        int rloc = M & 127;
        int xr = (rloc >> 1) & 3;
        size_t base2 = (((size_t)(M >> 7) * 6 + h) << 12) + rloc * 32;
        ob[base2 + (((c >> 3) ^ xr) << 3) + (c & 7)] = f2bf(o0[r] * inv);
        ob[base2 + ((((c >> 3) | 2) ^ xr) << 3) + (c & 7)] = f2bf(o1[r] * inv);
      }
    }
  }
}

// ---------------- output projection (r4 structure, unchanged): 64x192 tile,
// grid 686; obuf (written swizzled by attn) and pre-swizzled wpb staged via
// global_load_lds width-16 (1+3 DMAs per ktile, zero staging VALU); fp32 out.
__global__ __launch_bounds__(256) void proj_kernel(
    const unsigned short* __restrict__ obp, const unsigned short* __restrict__ wpb,
    const float* __restrict__ bvec, float* __restrict__ out) {
  __shared__ __align__(16) unsigned short SL[8192];   // 16KB
  unsigned short* XL = SL;            // 64x32 linear (swizzled chunks)
  unsigned short* WL = SL + 2048;     // 192x32 linear
  const int tid = threadIdx.x;
  const int wave = tid >> 6, lane = tid & 63;
  const int quad = lane >> 4, c = lane & 15;
  const int m0 = blockIdx.x * 64;
  const int mb = blockIdx.x >> 1;
  const int r0 = (blockIdx.x & 1) * 64;
  const int chk = (quad ^ ((c >> 1) & 3)) * 8;

  f32x4 acc[12];
#pragma unroll
  for (int j = 0; j < 12; ++j) acc[j] = (f32x4){0.f, 0.f, 0.f, 0.f};

  for (int kt = 0; kt < 6; ++kt) {
    const unsigned short* gx =
        obp + (((size_t)mb * 6 + kt) << 12) + r0 * 32 + tid * 8;
    const unsigned short* gw = wpb + (size_t)kt * 6144 + tid * 8;
    unsigned short* lx = XL + (size_t)wave * 512;
    unsigned short* lw = WL + (size_t)wave * 512;
    gload16(gx, lx);
    gload16(gw, lw);
    gload16(gw + 2048, lw + 2048);
    gload16(gw + 4096, lw + 4096);
    __syncthreads();
    short8 af = *(const short8*)&XL[(wave * 16 + c) * 32 + chk];
#pragma unroll
    for (int j = 0; j < 12; ++j) {
      short8 bfr = *(const short8*)&WL[(j * 16 + c) * 32 + chk];
      acc[j] = __builtin_amdgcn_mfma_f32_16x16x32_bf16(af, bfr, acc[j], 0, 0, 0);
    }
    __syncthreads();
  }

#pragma unroll
  for (int j = 0; j < 12; ++j) {
    int col = j * 16 + c;
    float bn = bvec[col];
#pragma unroll
    for (int r = 0; r < 4; ++r) {
      int m = m0 + wave * 16 + quad * 4 + r;
      out[(size_t)m * CD + col] = acc[j][r] + bn;
    }
  }
}

extern "C" void kernel_launch(void* const* d_in, const int* in_sizes, int n_in,
                              void* d_out, int out_size, void* d_ws, size_t ws_size,
                              hipStream_t stream) {
  const float* x      = (const float*)d_in[0];
  const float* mask   = (const float*)d_in[1];
  const float* qkv_w  = (const float*)d_in[2];
  const float* qkv_b  = (const float*)d_in[3];
  const float* proj_w = (const float*)d_in[4];
  const float* proj_b = (const float*)d_in[5];
  const float* rpb    = (const float*)d_in[6];
  const int*   rel    = (const int*)d_in[7];
  float* out = (float*)d_out;

  char* ws = (char*)d_ws;
  uint32_t* biasP = (uint32_t*)ws;                       // 6*61952*4 = 1,486,848
  size_t off = 1486848;
  uint32_t* maskP = (uint32_t*)(ws + off); off += 7929856;   // 32*61952*4
  unsigned short* qb = (unsigned short*)(ws + off); off += 16859136;
  unsigned short* kb = (unsigned short*)(ws + off); off += 16859136;
  unsigned short* vb = (unsigned short*)(ws + off); off += 16859136;
  unsigned short* wqb = (unsigned short*)(ws + off); off += 221184;
  unsigned short* wpb = (unsigned short*)(ws + off); off += 73728;
  unsigned short* xb  = (unsigned short*)(ws + off); off += 16859136;
  // obuf aliases xb: qkv finishes reading xb before attn writes it
  // (stream-ordered); prep rewrites xb each replay iteration.
  unsigned short* obuf = xb;

  hipLaunchKernelGGL(prep_cvt_kernel, dim3(54 + 18 + 4116), dim3(256), 0, stream,
                     qkv_w, proj_w, x, wqb, wpb, xb);
  hipLaunchKernelGGL(prep_bm_kernel, dim3(264 + 352), dim3(256), 0, stream,
                     rel, rpb, mask, biasP, maskP);
  hipLaunchKernelGGL(qkv_kernel, dim3(343, 3), dim3(256), 0, stream,
                     xb, wqb, qkv_b, qb, kb, vb);
  hipLaunchKernelGGL(attn_kernel, dim3(NH * NB), dim3(512), 0, stream,
                     qb, kb, vb, biasP, maskP, obuf);
  hipLaunchKernelGGL(proj_kernel, dim3(686), dim3(256), 0, stream,
                     obuf, wpb, proj_b, out);
}

// Round 7
// 215.768 us; speedup vs baseline: 1.2090x; 1.0177x over previous
//
#include <hip/hip_runtime.h>
#include <hip/hip_fp16.h>
#include <hip/hip_bf16.h>
#include <stdint.h>

#define WN 343       // tokens per window
#define NH 6         // heads
#define HD 32        // head dim
#define CD 192       // channels
#define NB 128       // windows (batch)
#define NWM 32       // mask windows
#define BMROW 352            // padded query dim
#define BMSLICE (11*16*BMROW) // dwords per slice = 61952
#define BMKC (16*BMROW)       // dwords per kc chunk = 5632
#define LOG2E 1.4426950408889634f

typedef __attribute__((ext_vector_type(8))) short short8;
typedef __attribute__((ext_vector_type(4))) float f32x4;

__device__ __forceinline__ unsigned short f2bf(float f) {
  union { float f; uint32_t u; } v; v.f = f;
  uint32_t r = v.u + 0x7fffu + ((v.u >> 16) & 1u);
  return (unsigned short)(r >> 16);
}

// packed f32x2 -> bf16x2 (v_cvt_pk_bf16_f32 on gfx950); low half = a
__device__ __forceinline__ uint32_t pk2bf(float a, float b) {
  __hip_bfloat162 h = __float22bfloat162_rn(make_float2(a, b));
  return *(uint32_t*)&h;
}

__device__ __forceinline__ uint32_t pkh2(float a, float b) {
  __half2 h; h.x = __float2half(a); h.y = __float2half(b);
  return *(uint32_t*)&h;
}

// async global->LDS, 16B per lane; LDS dest is wave-uniform base + lane*16
typedef const __attribute__((address_space(1))) unsigned int* gas_ptr;
typedef __attribute__((address_space(3))) unsigned int* las_ptr;
__device__ __forceinline__ void gload16(const unsigned short* g, unsigned short* l) {
  __builtin_amdgcn_global_load_lds((gas_ptr)(const void*)g, (las_ptr)(void*)l, 16, 0, 0);
}

// ---------------- prep (r7, single kernel): bias gather (264) | mask repack
// LDS-free (352) | wq swizzle (54) | wp swizzle (18) | x swizzle-cvt (4116).
// Static LDS is only the bias branch's M[88][33] floats (11.6KB) so no
// branch is occupancy-capped (r5/r6 lesson: 46KB LDS capped everything).
// bias/mask layout: slice[kc][quad][n][r] f16x2 words, pre-scaled log2(e);
// OOB keys: bias=-30000 (exp2 -> 0), mask=0. The rpb gather runs once per
// (h,kc,rowgroup) -- never per wdx (r4 lesson).
// wq/wp/x swizzled-tile layout: per 32-k tile, row-major 64B rows, 16B
// chunks permuted cc = lch ^ ((row>>1)&3); consumers stage LINEARLY via
// global_load_lds and read fragments at chunk (quad ^ ((c>>1)&3)).
__global__ __launch_bounds__(256) void prep_kernel(
    const float* __restrict__ wq, const float* __restrict__ wp,
    unsigned short* __restrict__ wqb, unsigned short* __restrict__ wpb,
    const int* __restrict__ rel, const float* __restrict__ rpb,
    const float* __restrict__ mask, uint32_t* __restrict__ bP,
    uint32_t* __restrict__ mP, const float* __restrict__ x,
    unsigned short* __restrict__ xb) {
  __shared__ float M[88][33];   // bias branch only, 11.6KB
  const int bid = blockIdx.x;
  const int tid = threadIdx.x;
  if (bid < 264) {
    // bias gather: 66 (h,kc) pairs x 4 row-groups of 88
    const int h = bid / 44;
    const int rem = bid - h * 44;
    const int kc = rem >> 2;
    const int g = rem & 3;
    const int n0 = g * 88;
    const int k0 = kc * 32;
    for (int idx = tid; idx < 88 * 32; idx += 256) {
      int nl = idx >> 5, k = idx & 31;
      int n = n0 + nl;
      int nc = (n < WN) ? n : (WN - 1);
      M[nl][k] = (k0 + k < WN) ? rpb[rel[nc * WN + k0 + k] * NH + h] * LOG2E
                               : -30000.0f;
    }
    __syncthreads();
    uint32_t* outp = bP + (size_t)h * BMSLICE + (size_t)kc * BMKC;
    if (tid < 88) {
      const int nl = tid;
      const int n = n0 + nl;
#pragma unroll
      for (int quad = 0; quad < 4; ++quad) {
        uint4 o;
        o.x = pkh2(M[nl][quad * 8 + 0], M[nl][quad * 8 + 4]);
        o.y = pkh2(M[nl][quad * 8 + 1], M[nl][quad * 8 + 5]);
        o.z = pkh2(M[nl][quad * 8 + 2], M[nl][quad * 8 + 6]);
        o.w = pkh2(M[nl][quad * 8 + 3], M[nl][quad * 8 + 7]);
        *(uint4*)(outp + ((size_t)quad * 352 + n) * 4) = o;
      }
    }
    return;
  }
  int cb = bid - 264;
  if (cb < 352) {
    // mask repack, LDS-free: each thread builds one output uint4 from 8
    // contiguous mask floats (32B/lane; full rows consumed within block)
    const int wdx = cb / 11;
    const int kc = cb - wdx * 11;
    const int k0 = kc * 32;
    const float* mw = mask + (size_t)wdx * (WN * WN);
    uint32_t* outp = mP + (size_t)wdx * BMSLICE + (size_t)kc * BMKC;
#pragma unroll
    for (int quad = 0; quad < 4; ++quad) {
      const int q8 = quad * 8;
#pragma unroll
      for (int j = 0; j < 2; ++j) {
        int n = tid + 256 * j;
        if (n < 352) {
          float v[8];
#pragma unroll
          for (int i = 0; i < 8; ++i) {
            int kk = k0 + q8 + i;
            v[i] = (n < WN && kk < WN) ? mw[n * WN + kk] * LOG2E : 0.0f;
          }
          uint4 o;
          o.x = pkh2(v[0], v[4]);
          o.y = pkh2(v[1], v[5]);
          o.z = pkh2(v[2], v[6]);
          o.w = pkh2(v[3], v[7]);
          *(uint4*)(outp + ((size_t)quad * 352 + n) * 4) = o;
        }
      }
    }
    return;
  }
  cb -= 352;
  if (cb < 54) {
    // wq -> swizzled bf16 tiles: 18 tiles (s*6+kt) x 192 rows x 4 chunks
    int g = cb * 256 + tid;            // < 13824
    int sk = g / 768; int rem = g - sk * 768;
    int row = rem >> 2; int cc = rem & 3;
    int s = sk / 6; int kt = sk - s * 6;
    int lch = cc ^ ((row >> 1) & 3);
    const float* src = wq + (size_t)(s * 192 + row) * CD + kt * 32 + lch * 8;
    f32x4 a = *(const f32x4*)src;
    f32x4 b = *(const f32x4*)(src + 4);
    union { short8 v8; uint32_t d[4]; } pk;
    pk.d[0] = pk2bf(a[0], a[1]);
    pk.d[1] = pk2bf(a[2], a[3]);
    pk.d[2] = pk2bf(b[0], b[1]);
    pk.d[3] = pk2bf(b[2], b[3]);
    *(short8*)(wqb + (size_t)g * 8) = pk.v8;
    return;
  }
  cb -= 54;
  if (cb < 18) {
    // wp -> swizzled bf16 tiles: 6 tiles (kt) x 192 rows x 4 chunks
    int g = cb * 256 + tid;            // < 4608
    int kt = g / 768; int rem = g - kt * 768;
    int row = rem >> 2; int cc = rem & 3;
    int lch = cc ^ ((row >> 1) & 3);
    const float* src = wp + (size_t)row * CD + kt * 32 + lch * 8;
    f32x4 a = *(const f32x4*)src;
    f32x4 b = *(const f32x4*)(src + 4);
    union { short8 v8; uint32_t d[4]; } pk;
    pk.d[0] = pk2bf(a[0], a[1]);
    pk.d[1] = pk2bf(a[2], a[3]);
    pk.d[2] = pk2bf(b[0], b[1]);
    pk.d[3] = pk2bf(b[2], b[3]);
    *(short8*)(wpb + (size_t)g * 8) = pk.v8;
    return;
  }
  cb -= 18;
  // x -> swizzled bf16 tiles: 343*6 tiles x 128 rows x 4 chunks
  size_t gx = (size_t)cb * 256 + tid;  // < 1,053,696
  int tile = (int)(gx >> 9); int rem = (int)(gx & 511);
  int row = rem >> 2; int cc = rem & 3;
  int mb = tile / 6; int kt = tile - mb * 6;
  int lch = cc ^ ((row >> 1) & 3);
  const float* src = x + ((size_t)mb * 128 + row) * CD + kt * 32 + lch * 8;
  f32x4 a = *(const f32x4*)src;
  f32x4 b = *(const f32x4*)(src + 4);
  union { short8 v8; uint32_t d[4]; } pk;
  pk.d[0] = pk2bf(a[0], a[1]);
  pk.d[1] = pk2bf(a[2], a[3]);
  pk.d[2] = pk2bf(b[0], b[1]);
  pk.d[3] = pk2bf(b[2], b[3]);
  *(short8*)(xb + gx * 8) = pk.v8;
}

// ---------------- QKV GEMM (r3 structure, unchanged): 128x192 tile, 6
// ktiles, 2 barriers each, staging via global_load_lds width-16 from the
// pre-swizzled bf16 xb/wqb. Epilogue repack (stride 36) overlays staging LDS.
__global__ __launch_bounds__(256) void qkv_kernel(
    const unsigned short* __restrict__ xb, const unsigned short* __restrict__ wqb,
    const float* __restrict__ bvec,
    unsigned short* __restrict__ qb, unsigned short* __restrict__ kb,
    unsigned short* __restrict__ vb) {
  __shared__ __align__(16) unsigned short SL[10240];   // 20KB
  unsigned short* XL = SL;            // 128x32 linear (swizzled chunks)
  unsigned short* WL = SL + 4096;     // 192x32 linear
  const int tid = threadIdx.x;
  const int wave = tid >> 6, lane = tid & 63;
  const int quad = lane >> 4, c = lane & 15;
  const int m0 = blockIdx.x * 128;
  const int s = blockIdx.y;            // 0=q, 1=k, 2=v
  const int chk = (quad ^ ((c >> 1) & 3)) * 8;

  f32x4 acc[2][12];
#pragma unroll
  for (int i = 0; i < 2; ++i)
#pragma unroll
    for (int j = 0; j < 12; ++j) acc[i][j] = (f32x4){0.f, 0.f, 0.f, 0.f};

  const size_t xt0 = (size_t)blockIdx.x * 6;
  const size_t wt0 = (size_t)s * 6;
  for (int kt = 0; kt < 6; ++kt) {
    const unsigned short* gx = xb + ((xt0 + kt) << 12) + tid * 8;
    const unsigned short* gw = wqb + (wt0 + kt) * 6144 + tid * 8;
    unsigned short* lx = XL + (size_t)wave * 512;   // wave-uniform, 1KB/wave
    unsigned short* lw = WL + (size_t)wave * 512;
    gload16(gx, lx);
    gload16(gx + 2048, lx + 2048);
    gload16(gw, lw);
    gload16(gw + 2048, lw + 2048);
    gload16(gw + 4096, lw + 4096);
    __syncthreads();
    short8 af0 = *(const short8*)&XL[(wave * 32 + c) * 32 + chk];
    short8 af1 = *(const short8*)&XL[(wave * 32 + 16 + c) * 32 + chk];
#pragma unroll
    for (int j = 0; j < 12; ++j) {
      short8 bfr = *(const short8*)&WL[(j * 16 + c) * 32 + chk];
      acc[0][j] = __builtin_amdgcn_mfma_f32_16x16x32_bf16(af0, bfr, acc[0][j], 0, 0, 0);
      acc[1][j] = __builtin_amdgcn_mfma_f32_16x16x32_bf16(af1, bfr, acc[1][j], 0, 0, 0);
    }
    __syncthreads();
  }

  // q scale folded with log2(e): 32^-0.5 * 1.4426950409 (softmax runs in
  // exp2 domain; bias/mask pre-scaled by log2(e) in prep)
  const float qscale = 0.25503486f;
  unsigned short* dst = (s == 0) ? qb : ((s == 1) ? kb : vb);
  const float scl = (s == 0) ? qscale : 1.0f;
  const int n0 = s * 192;
  // repack overlays dead staging LDS; stride 36 shorts -> all-32-bank writes
  unsigned short* Lh0 = SL;            // 128 rows x 36
  unsigned short* Lh1 = SL + 4608;
  for (int hh = 0; hh < 3; ++hh) {
    __syncthreads();
#pragma unroll
    for (int jj = 0; jj < 4; ++jj) {
      int j = hh * 4 + jj;
      int hl = jj >> 1;
      int dd = (jj & 1) * 16 + c;
      float bn = bvec[n0 + j * 16 + c];
      unsigned short* L = hl ? Lh1 : Lh0;
#pragma unroll
      for (int i = 0; i < 2; ++i)
#pragma unroll
        for (int r = 0; r < 4; ++r) {
          int m = wave * 32 + i * 16 + quad * 4 + r;
          L[m * 36 + dd] = f2bf((acc[i][j][r] + bn) * scl);
        }
    }
    __syncthreads();
    const int m = tid & 127;
    const int hl = tid >> 7;
    const int M = m0 + m;
    const int b = M / WN;
    const int tok = M - b * WN;
    const int h = hh * 2 + hl;
    const unsigned short* L = hl ? Lh1 : Lh0;
    unsigned short* drow = dst + (((size_t)b * NH + h) * WN + tok) * HD;
#pragma unroll
    for (int t2 = 0; t2 < 4; ++t2) {
      int d0 = t2 * 8;
      *(short8*)&drow[d0] = *(const short8*)&L[m * 36 + d0];
    }
  }
}

// ---------------- fused attention (r7): VALU diet + pipeline.
// (a) softmax denominator via a 3rd PV MFMA against a bf16-ones fragment:
//     accl[r] = sum_k P[q][k] lands at the SAME lane/reg as o0[r]/o1[r]
//     -> deletes 8 v_add per kc AND all shuffles (MFMA pipe was 91% idle).
// (b) kc loop unroll 1 + manual depth-2 prefetch of bias/mask dwordx4
//     (branchless clamped index) -> load latency off the critical path
//     with a SMALLER live set (VGPR must stay <=128: 129 would halve
//     occupancy; r6 measured 124 at unroll-2).
// (c) s_setprio(1) around MFMA clusters (T5: +4-7% on attn-like kernels).
// Two C-operand loads per kc (bias 1.5MB + mask 7.9MB, both L2-resident
// with XCD clustering; r5 lesson: materializing the sum spills L2).
// NOTE: plain __launch_bounds__ — a min-waves arg makes the allocator cap
// VGPRs and spill (r5: +29MB).
__global__ __launch_bounds__(512) void attn_kernel(
    const unsigned short* __restrict__ qb, const unsigned short* __restrict__ kb,
    const unsigned short* __restrict__ vb, const uint32_t* __restrict__ biasP,
    const uint32_t* __restrict__ maskP, unsigned short* __restrict__ ob) {
  __shared__ __align__(16) unsigned short Ks[352][40];  // [perm key row][d]
  __shared__ __align__(16) unsigned short Vt[HD][360];  // [d][key]
  // XCD swizzle: bid%8 = XCD (observed round-robin); job groups of 24 share wdx
  const int bid = blockIdx.x;
  const int job = (bid & 7) * 96 + (bid >> 3);
  const int wdx = job / 24;
  const int inner = job - wdx * 24;
  const int h = inner >> 2;
  const int b = (inner & 3) * 32 + wdx;   // preserves wdx == b & 31
  const int tid = threadIdx.x;
  const int wave = tid >> 6, lane = tid & 63;
  const int quad = lane >> 4, c = lane & 15;
  const size_t base = ((size_t)b * NH + h) * (WN * HD);
  const unsigned short* q = qb + base;
  const unsigned short* k = kb + base;
  const unsigned short* v = vb + base;
  const uint32_t* bS = biasP + (size_t)h * BMSLICE;
  const uint32_t* mS = maskP + (size_t)wdx * BMSLICE;

  // stage K with permuted rows
  for (int t = tid; t < WN * 4; t += 512) {
    int r = t >> 2, ch = t & 3;
    int kk = r & 31;
    int row = (r & ~31) + 16 * ((kk >> 2) & 1) + 4 * (kk >> 3) + (kk & 3);
    *(short8*)&Ks[row][ch * 8] = *(const short8*)(k + r * HD + ch * 8);
  }
  for (int t = tid; t < 9 * 32; t += 512) {
    int kg = WN + (t >> 5);
    int kk = kg & 31;
    int row = (kg & ~31) + 16 * ((kk >> 2) & 1) + 4 * (kk >> 3) + (kk & 3);
    Ks[row][t & 31] = 0;
  }
  // stage V transposed, natural key order
  for (int t = tid; t < WN; t += 512) {
#pragma unroll
    for (int ch = 0; ch < 4; ++ch) {
      short8 vv = *(const short8*)(v + t * HD + ch * 8);
#pragma unroll
      for (int j = 0; j < 8; ++j) Vt[ch * 8 + j][t] = vv[j];
    }
  }
  for (int t = tid; t < 9 * 32; t += 512) {
    Vt[t & 31][WN + (t >> 5)] = 0;
  }
  __syncthreads();

  // bf16 ones fragment for the row-sum MFMA
  union { short8 v8; uint32_t d[4]; } on;
  on.d[0] = on.d[1] = on.d[2] = on.d[3] = 0x3F803F80u;

  for (int qt = wave; qt < 22; qt += 8) {
    const int q0 = qt * 16;
    int qr = q0 + c; if (qr > WN - 1) qr = WN - 1;
    const short8 qf = *(const short8*)(q + qr * HD + quad * 8);
    const uint32_t* bRow = bS + ((size_t)quad * 352 + q0 + c) * 4;
    const uint32_t* mRow = mS + ((size_t)quad * 352 + q0 + c) * 4;

    f32x4 o0 = (f32x4){0.f, 0.f, 0.f, 0.f};
    f32x4 o1 = (f32x4){0.f, 0.f, 0.f, 0.f};
    f32x4 accl = (f32x4){0.f, 0.f, 0.f, 0.f};
    uint4 bw = *(const uint4*)bRow;
    uint4 mw = *(const uint4*)mRow;
#pragma unroll 1
    for (int kc = 0; kc < 11; ++kc) {
      const int kcn = (kc < 10) ? kc + 1 : 10;   // clamped: branchless prefetch
      uint4 bwN = *(const uint4*)(bRow + (size_t)kcn * BMKC);
      uint4 mwN = *(const uint4*)(mRow + (size_t)kcn * BMKC);
      // C-operand = log2e*(bias+mask) for this lane's 8 keys
      f32x4 cc0, cc1;
      {
        __half2 s2; float2 f;
        s2 = __hadd2(*(__half2*)&bw.x, *(__half2*)&mw.x);
        f = __half22float2(s2); cc0[0] = f.x; cc1[0] = f.y;
        s2 = __hadd2(*(__half2*)&bw.y, *(__half2*)&mw.y);
        f = __half22float2(s2); cc0[1] = f.x; cc1[1] = f.y;
        s2 = __hadd2(*(__half2*)&bw.z, *(__half2*)&mw.z);
        f = __half22float2(s2); cc0[2] = f.x; cc1[2] = f.y;
        s2 = __hadd2(*(__half2*)&bw.w, *(__half2*)&mw.w);
        f = __half22float2(s2); cc0[3] = f.x; cc1[3] = f.y;
      }
      const int k0 = kc * 32;
      short8 kf0 = *(const short8*)&Ks[k0 + c][quad * 8];
      short8 kf1 = *(const short8*)&Ks[k0 + 16 + c][quad * 8];
      __builtin_amdgcn_s_setprio(1);
      f32x4 s0 = __builtin_amdgcn_mfma_f32_16x16x32_bf16(kf0, qf, cc0, 0, 0, 0);
      f32x4 s1 = __builtin_amdgcn_mfma_f32_16x16x32_bf16(kf1, qf, cc1, 0, 0, 0);
      __builtin_amdgcn_s_setprio(0);
      // scores in log2 domain -> direct v_exp_f32 (2^x), unnormalized;
      // OOB keys carry -30000 -> exp2==0
      float p0 = __builtin_amdgcn_exp2f(s0[0]), p1 = __builtin_amdgcn_exp2f(s0[1]);
      float p2 = __builtin_amdgcn_exp2f(s0[2]), p3 = __builtin_amdgcn_exp2f(s0[3]);
      float p4 = __builtin_amdgcn_exp2f(s1[0]), p5 = __builtin_amdgcn_exp2f(s1[1]);
      float p6 = __builtin_amdgcn_exp2f(s1[2]), p7 = __builtin_amdgcn_exp2f(s1[3]);
      union { short8 v8; uint32_t d[4]; } pf;
      pf.d[0] = pk2bf(p0, p1);
      pf.d[1] = pk2bf(p2, p3);
      pf.d[2] = pk2bf(p4, p5);
      pf.d[3] = pk2bf(p6, p7);
      short8 vf0 = *(const short8*)&Vt[c][k0 + quad * 8];
      short8 vf1 = *(const short8*)&Vt[16 + c][k0 + quad * 8];
      __builtin_amdgcn_s_setprio(1);
      o0 = __builtin_amdgcn_mfma_f32_16x16x32_bf16(pf.v8, vf0, o0, 0, 0, 0);
      o1 = __builtin_amdgcn_mfma_f32_16x16x32_bf16(pf.v8, vf1, o1, 0, 0, 0);
      accl = __builtin_amdgcn_mfma_f32_16x16x32_bf16(pf.v8, on.v8, accl, 0, 0, 0);
      __builtin_amdgcn_s_setprio(0);
      bw = bwN; mw = mwN;
    }

    // Epilogue: O rows m=quad*4+r are queries q0+m; accl[r] = l for that
    // query at the SAME lane (no shuffles). Store into swizzled tile layout:
    // tile (M>>7, kt=h), row M&127, chunk lch ^ ((row>>1)&3) -- proj reads
    // via global_load_lds.
#pragma unroll
    for (int r = 0; r < 4; ++r) {
      int n = q0 + quad * 4 + r;
      if (n < WN) {
        float inv = 1.0f / accl[r];
        int M = b * WN + n;
        int rloc = M & 127;
        int xr = (rloc >> 1) & 3;
        size_t base2 = (((size_t)(M >> 7) * 6 + h) << 12) + rloc * 32;
        ob[base2 + (((c >> 3) ^ xr) << 3) + (c & 7)] = f2bf(o0[r] * inv);
        ob[base2 + ((((c >> 3) | 2) ^ xr) << 3) + (c & 7)] = f2bf(o1[r] * inv);
      }
    }
  }
}

// ---------------- output projection (r4 structure, unchanged): 64x192 tile,
// grid 686; obuf (written swizzled by attn) and pre-swizzled wpb staged via
// global_load_lds width-16 (1+3 DMAs per ktile, zero staging VALU); fp32 out.
__global__ __launch_bounds__(256) void proj_kernel(
    const unsigned short* __restrict__ obp, const unsigned short* __restrict__ wpb,
    const float* __restrict__ bvec, float* __restrict__ out) {
  __shared__ __align__(16) unsigned short SL[8192];   // 16KB
  unsigned short* XL = SL;            // 64x32 linear (swizzled chunks)
  unsigned short* WL = SL + 2048;     // 192x32 linear
  const int tid = threadIdx.x;
  const int wave = tid >> 6, lane = tid & 63;
  const int quad = lane >> 4, c = lane & 15;
  const int m0 = blockIdx.x * 64;
  const int mb = blockIdx.x >> 1;
  const int r0 = (blockIdx.x & 1) * 64;
  const int chk = (quad ^ ((c >> 1) & 3)) * 8;

  f32x4 acc[12];
#pragma unroll
  for (int j = 0; j < 12; ++j) acc[j] = (f32x4){0.f, 0.f, 0.f, 0.f};

  for (int kt = 0; kt < 6; ++kt) {
    const unsigned short* gx =
        obp + (((size_t)mb * 6 + kt) << 12) + r0 * 32 + tid * 8;
    const unsigned short* gw = wpb + (size_t)kt * 6144 + tid * 8;
    unsigned short* lx = XL + (size_t)wave * 512;
    unsigned short* lw = WL + (size_t)wave * 512;
    gload16(gx, lx);
    gload16(gw, lw);
    gload16(gw + 2048, lw + 2048);
    gload16(gw + 4096, lw + 4096);
    __syncthreads();
    short8 af = *(const short8*)&XL[(wave * 16 + c) * 32 + chk];
#pragma unroll
    for (int j = 0; j < 12; ++j) {
      short8 bfr = *(const short8*)&WL[(j * 16 + c) * 32 + chk];
      acc[j] = __builtin_amdgcn_mfma_f32_16x16x32_bf16(af, bfr, acc[j], 0, 0, 0);
    }
    __syncthreads();
  }

#pragma unroll
  for (int j = 0; j < 12; ++j) {
    int col = j * 16 + c;
    float bn = bvec[col];
#pragma unroll
    for (int r = 0; r < 4; ++r) {
      int m = m0 + wave * 16 + quad * 4 + r;
      out[(size_t)m * CD + col] = acc[j][r] + bn;
    }
  }
}

extern "C" void kernel_launch(void* const* d_in, const int* in_sizes, int n_in,
                              void* d_out, int out_size, void* d_ws, size_t ws_size,
                              hipStream_t stream) {
  const float* x      = (const float*)d_in[0];
  const float* mask   = (const float*)d_in[1];
  const float* qkv_w  = (const float*)d_in[2];
  const float* qkv_b  = (const float*)d_in[3];
  const float* proj_w = (const float*)d_in[4];
  const float* proj_b = (const float*)d_in[5];
  const float* rpb    = (const float*)d_in[6];
  const int*   rel    = (const int*)d_in[7];
  float* out = (float*)d_out;

  char* ws = (char*)d_ws;
  uint32_t* biasP = (uint32_t*)ws;                       // 6*61952*4 = 1,486,848
  size_t off = 1486848;
  uint32_t* maskP = (uint32_t*)(ws + off); off += 7929856;   // 32*61952*4
  unsigned short* qb = (unsigned short*)(ws + off); off += 16859136;
  unsigned short* kb = (unsigned short*)(ws + off); off += 16859136;
  unsigned short* vb = (unsigned short*)(ws + off); off += 16859136;
  unsigned short* wqb = (unsigned short*)(ws + off); off += 221184;
  unsigned short* wpb = (unsigned short*)(ws + off); off += 73728;
  unsigned short* xb  = (unsigned short*)(ws + off); off += 16859136;
  // obuf aliases xb: qkv finishes reading xb before attn writes it
  // (stream-ordered); prep rewrites xb each replay iteration.
  unsigned short* obuf = xb;

  hipLaunchKernelGGL(prep_kernel, dim3(264 + 352 + 54 + 18 + 4116), dim3(256),
                     0, stream,
                     qkv_w, proj_w, wqb, wpb, rel, rpb, mask, biasP, maskP, x, xb);
  hipLaunchKernelGGL(qkv_kernel, dim3(343, 3), dim3(256), 0, stream,
                     xb, wqb, qkv_b, qb, kb, vb);
  hipLaunchKernelGGL(attn_kernel, dim3(NH * NB), dim3(512), 0, stream,
                     qb, kb, vb, biasP, maskP, obuf);
  hipLaunchKernelGGL(proj_kernel, dim3(686), dim3(256), 0, stream,
                     obuf, wpb, proj_b, out);
}

// Round 8
// 211.871 us; speedup vs baseline: 1.2312x; 1.0184x over previous
//
#include <hip/hip_runtime.h>
#include <hip/hip_fp16.h>
#include <hip/hip_bf16.h>
#include <stdint.h>

#define WN 343       // tokens per window
#define NH 6         // heads
#define HD 32        // head dim
#define CD 192       // channels
#define NB 128       // windows (batch)
#define NWM 32       // mask windows
#define BMROW 352            // padded query dim
#define BMSLICE (11*16*BMROW) // dwords per slice = 61952
#define BMKC (16*BMROW)       // dwords per kc chunk = 5632
#define LOG2E 1.4426950408889634f

typedef __attribute__((ext_vector_type(8))) short short8;
typedef __attribute__((ext_vector_type(4))) float f32x4;

__device__ __forceinline__ unsigned short f2bf(float f) {
  union { float f; uint32_t u; } v; v.f = f;
  uint32_t r = v.u + 0x7fffu + ((v.u >> 16) & 1u);
  return (unsigned short)(r >> 16);
}

// packed f32x2 -> bf16x2 (v_cvt_pk_bf16_f32 on gfx950); low half = a
__device__ __forceinline__ uint32_t pk2bf(float a, float b) {
  __hip_bfloat162 h = __float22bfloat162_rn(make_float2(a, b));
  return *(uint32_t*)&h;
}

__device__ __forceinline__ uint32_t pkh2(float a, float b) {
  __half2 h; h.x = __float2half(a); h.y = __float2half(b);
  return *(uint32_t*)&h;
}

// async global->LDS, 16B per lane; LDS dest is wave-uniform base + lane*16
typedef const __attribute__((address_space(1))) unsigned int* gas_ptr;
typedef __attribute__((address_space(3))) unsigned int* las_ptr;
__device__ __forceinline__ void gload16(const unsigned short* g, unsigned short* l) {
  __builtin_amdgcn_global_load_lds((gas_ptr)(const void*)g, (las_ptr)(void*)l, 16, 0, 0);
}

// 2-phase pipeline barrier (T3 minimal): manual vmcnt drain + RAW s_barrier.
// __syncthreads() would emit its own vmcnt(0) BEFORE issuing-order allowed
// overlap; here the in-flight DMAs issued this phase had the whole MFMA
// phase to land. sched_barrier(0) fences (rule #18: hipcc hoists past asm).
__device__ __forceinline__ void pipe_bar() {
  asm volatile("s_waitcnt vmcnt(0) lgkmcnt(0)" ::: "memory");
  __builtin_amdgcn_sched_barrier(0);
  __builtin_amdgcn_s_barrier();
  __builtin_amdgcn_sched_barrier(0);
}

// ---------------- prep (r7 structure, unchanged): bias gather (264) | mask
// repack LDS-free (352) | wq swizzle (54) | wp swizzle (18) | x swizzle-cvt
// (4116). Static LDS only M[88][33] (11.6KB). bias/mask pre-scaled log2(e);
// OOB keys: bias=-30000 (exp2 -> 0), mask=0. rpb gather once per
// (h,kc,rowgroup) -- never per wdx (r4 lesson).
__global__ __launch_bounds__(256) void prep_kernel(
    const float* __restrict__ wq, const float* __restrict__ wp,
    unsigned short* __restrict__ wqb, unsigned short* __restrict__ wpb,
    const int* __restrict__ rel, const float* __restrict__ rpb,
    const float* __restrict__ mask, uint32_t* __restrict__ bP,
    uint32_t* __restrict__ mP, const float* __restrict__ x,
    unsigned short* __restrict__ xb) {
  __shared__ float M[88][33];   // bias branch only, 11.6KB
  const int bid = blockIdx.x;
  const int tid = threadIdx.x;
  if (bid < 264) {
    // bias gather: 66 (h,kc) pairs x 4 row-groups of 88
    const int h = bid / 44;
    const int rem = bid - h * 44;
    const int kc = rem >> 2;
    const int g = rem & 3;
    const int n0 = g * 88;
    const int k0 = kc * 32;
    for (int idx = tid; idx < 88 * 32; idx += 256) {
      int nl = idx >> 5, k = idx & 31;
      int n = n0 + nl;
      int nc = (n < WN) ? n : (WN - 1);
      M[nl][k] = (k0 + k < WN) ? rpb[rel[nc * WN + k0 + k] * NH + h] * LOG2E
                               : -30000.0f;
    }
    __syncthreads();
    uint32_t* outp = bP + (size_t)h * BMSLICE + (size_t)kc * BMKC;
    if (tid < 88) {
      const int nl = tid;
      const int n = n0 + nl;
#pragma unroll
      for (int quad = 0; quad < 4; ++quad) {
        uint4 o;
        o.x = pkh2(M[nl][quad * 8 + 0], M[nl][quad * 8 + 4]);
        o.y = pkh2(M[nl][quad * 8 + 1], M[nl][quad * 8 + 5]);
        o.z = pkh2(M[nl][quad * 8 + 2], M[nl][quad * 8 + 6]);
        o.w = pkh2(M[nl][quad * 8 + 3], M[nl][quad * 8 + 7]);
        *(uint4*)(outp + ((size_t)quad * 352 + n) * 4) = o;
      }
    }
    return;
  }
  int cb = bid - 264;
  if (cb < 352) {
    // mask repack, LDS-free
    const int wdx = cb / 11;
    const int kc = cb - wdx * 11;
    const int k0 = kc * 32;
    const float* mw = mask + (size_t)wdx * (WN * WN);
    uint32_t* outp = mP + (size_t)wdx * BMSLICE + (size_t)kc * BMKC;
#pragma unroll
    for (int quad = 0; quad < 4; ++quad) {
      const int q8 = quad * 8;
#pragma unroll
      for (int j = 0; j < 2; ++j) {
        int n = tid + 256 * j;
        if (n < 352) {
          float v[8];
#pragma unroll
          for (int i = 0; i < 8; ++i) {
            int kk = k0 + q8 + i;
            v[i] = (n < WN && kk < WN) ? mw[n * WN + kk] * LOG2E : 0.0f;
          }
          uint4 o;
          o.x = pkh2(v[0], v[4]);
          o.y = pkh2(v[1], v[5]);
          o.z = pkh2(v[2], v[6]);
          o.w = pkh2(v[3], v[7]);
          *(uint4*)(outp + ((size_t)quad * 352 + n) * 4) = o;
        }
      }
    }
    return;
  }
  cb -= 352;
  if (cb < 54) {
    // wq -> swizzled bf16 tiles: 18 tiles (s*6+kt) x 192 rows x 4 chunks
    int g = cb * 256 + tid;            // < 13824
    int sk = g / 768; int rem = g - sk * 768;
    int row = rem >> 2; int cc = rem & 3;
    int s = sk / 6; int kt = sk - s * 6;
    int lch = cc ^ ((row >> 1) & 3);
    const float* src = wq + (size_t)(s * 192 + row) * CD + kt * 32 + lch * 8;
    f32x4 a = *(const f32x4*)src;
    f32x4 b = *(const f32x4*)(src + 4);
    union { short8 v8; uint32_t d[4]; } pk;
    pk.d[0] = pk2bf(a[0], a[1]);
    pk.d[1] = pk2bf(a[2], a[3]);
    pk.d[2] = pk2bf(b[0], b[1]);
    pk.d[3] = pk2bf(b[2], b[3]);
    *(short8*)(wqb + (size_t)g * 8) = pk.v8;
    return;
  }
  cb -= 54;
  if (cb < 18) {
    // wp -> swizzled bf16 tiles: 6 tiles (kt) x 192 rows x 4 chunks
    int g = cb * 256 + tid;            // < 4608
    int kt = g / 768; int rem = g - kt * 768;
    int row = rem >> 2; int cc = rem & 3;
    int lch = cc ^ ((row >> 1) & 3);
    const float* src = wp + (size_t)row * CD + kt * 32 + lch * 8;
    f32x4 a = *(const f32x4*)src;
    f32x4 b = *(const f32x4*)(src + 4);
    union { short8 v8; uint32_t d[4]; } pk;
    pk.d[0] = pk2bf(a[0], a[1]);
    pk.d[1] = pk2bf(a[2], a[3]);
    pk.d[2] = pk2bf(b[0], b[1]);
    pk.d[3] = pk2bf(b[2], b[3]);
    *(short8*)(wpb + (size_t)g * 8) = pk.v8;
    return;
  }
  cb -= 18;
  // x -> swizzled bf16 tiles: 343*6 tiles x 128 rows x 4 chunks
  size_t gx = (size_t)cb * 256 + tid;  // < 1,053,696
  int tile = (int)(gx >> 9); int rem = (int)(gx & 511);
  int row = rem >> 2; int cc = rem & 3;
  int mb = tile / 6; int kt = tile - mb * 6;
  int lch = cc ^ ((row >> 1) & 3);
  const float* src = x + ((size_t)mb * 128 + row) * CD + kt * 32 + lch * 8;
  f32x4 a = *(const f32x4*)src;
  f32x4 b = *(const f32x4*)(src + 4);
  union { short8 v8; uint32_t d[4]; } pk;
  pk.d[0] = pk2bf(a[0], a[1]);
  pk.d[1] = pk2bf(a[2], a[3]);
  pk.d[2] = pk2bf(b[0], b[1]);
  pk.d[3] = pk2bf(b[2], b[3]);
  *(short8*)(xb + gx * 8) = pk.v8;
}

// ---------------- QKV GEMM (r8): 2-phase double-buffered pipeline. 40KB LDS
// (2 x {XL 8KB + WL 12KB}); blocks/CU still 4 (VGPR-capped, not LDS-capped).
// Per tile: issue next-tile DMAs -> ds_read+24 MFMA on current -> ONE
// vmcnt(0)+s_barrier (was 2 __syncthreads, each draining DMAs with zero
// overlap -- the m97-structure stall). Epilogue repack overlays buf0.
__global__ __launch_bounds__(256) void qkv_kernel(
    const unsigned short* __restrict__ xb, const unsigned short* __restrict__ wqb,
    const float* __restrict__ bvec,
    unsigned short* __restrict__ qb, unsigned short* __restrict__ kb,
    unsigned short* __restrict__ vb) {
  __shared__ __align__(16) unsigned short SL[20480];   // 40KB, two 10240 bufs
  const int tid = threadIdx.x;
  const int wave = tid >> 6, lane = tid & 63;
  const int quad = lane >> 4, c = lane & 15;
  const int m0 = blockIdx.x * 128;
  const int s = blockIdx.y;            // 0=q, 1=k, 2=v
  const int chk = (quad ^ ((c >> 1) & 3)) * 8;

  f32x4 acc[2][12];
#pragma unroll
  for (int i = 0; i < 2; ++i)
#pragma unroll
    for (int j = 0; j < 12; ++j) acc[i][j] = (f32x4){0.f, 0.f, 0.f, 0.f};

  const size_t xt0 = (size_t)blockIdx.x * 6;
  const size_t wt0 = (size_t)s * 6;

  auto STAGE = [&](unsigned short* buf, int kt) {
    const unsigned short* gx = xb + ((xt0 + kt) << 12) + tid * 8;
    const unsigned short* gw = wqb + (wt0 + kt) * 6144 + tid * 8;
    unsigned short* lx = buf + (size_t)wave * 512;          // XL region
    unsigned short* lw = buf + 4096 + (size_t)wave * 512;   // WL region
    gload16(gx, lx);
    gload16(gx + 2048, lx + 2048);
    gload16(gw, lw);
    gload16(gw + 2048, lw + 2048);
    gload16(gw + 4096, lw + 4096);
  };
  auto COMPUTE = [&](const unsigned short* buf) {
    const unsigned short* XLb = buf;
    const unsigned short* WLb = buf + 4096;
    short8 af0 = *(const short8*)&XLb[(wave * 32 + c) * 32 + chk];
    short8 af1 = *(const short8*)&XLb[(wave * 32 + 16 + c) * 32 + chk];
#pragma unroll
    for (int j = 0; j < 12; ++j) {
      short8 bfr = *(const short8*)&WLb[(j * 16 + c) * 32 + chk];
      acc[0][j] = __builtin_amdgcn_mfma_f32_16x16x32_bf16(af0, bfr, acc[0][j], 0, 0, 0);
      acc[1][j] = __builtin_amdgcn_mfma_f32_16x16x32_bf16(af1, bfr, acc[1][j], 0, 0, 0);
    }
  };

  unsigned short* B0 = SL;
  unsigned short* B1 = SL + 10240;
  STAGE(B0, 0);
  pipe_bar();
#pragma unroll
  for (int p = 0; p < 3; ++p) {
    STAGE(B1, 2 * p + 1);       // issue next while computing current
    COMPUTE(B0);                // tile 2p
    pipe_bar();
    if (p < 2) STAGE(B0, 2 * p + 2);
    COMPUTE(B1);                // tile 2p+1
    pipe_bar();
  }

  // q scale folded with log2(e): 32^-0.5 * 1.4426950409 (softmax runs in
  // exp2 domain; bias/mask pre-scaled by log2(e) in prep)
  const float qscale = 0.25503486f;
  unsigned short* dst = (s == 0) ? qb : ((s == 1) ? kb : vb);
  const float scl = (s == 0) ? qscale : 1.0f;
  const int n0 = s * 192;
  // repack overlays dead staging LDS; stride 36 shorts -> all-32-bank writes
  unsigned short* Lh0 = SL;            // 128 rows x 36
  unsigned short* Lh1 = SL + 4608;
  for (int hh = 0; hh < 3; ++hh) {
    __syncthreads();
#pragma unroll
    for (int jj = 0; jj < 4; ++jj) {
      int j = hh * 4 + jj;
      int hl = jj >> 1;
      int dd = (jj & 1) * 16 + c;
      float bn = bvec[n0 + j * 16 + c];
      unsigned short* L = hl ? Lh1 : Lh0;
#pragma unroll
      for (int i = 0; i < 2; ++i)
#pragma unroll
        for (int r = 0; r < 4; ++r) {
          int m = wave * 32 + i * 16 + quad * 4 + r;
          L[m * 36 + dd] = f2bf((acc[i][j][r] + bn) * scl);
        }
    }
    __syncthreads();
    const int m = tid & 127;
    const int hl = tid >> 7;
    const int M = m0 + m;
    const int b = M / WN;
    const int tok = M - b * WN;
    const int h = hh * 2 + hl;
    const unsigned short* L = hl ? Lh1 : Lh0;
    unsigned short* drow = dst + (((size_t)b * NH + h) * WN + tok) * HD;
#pragma unroll
    for (int t2 = 0; t2 < 4; ++t2) {
      int d0 = t2 * 8;
      *(short8*)&drow[d0] = *(const short8*)&L[m * 36 + d0];
    }
  }
}

// ---------------- fused attention (r7 structure + pointer-increment
// prefetch): accl row-sum via 3rd PV MFMA (no shuffles), depth-2 bias/mask
// prefetch now advances POINTERS unconditionally (kc=10 prefetch reads one
// mapped-but-unused chunk past the slice -- branchless, no clamp mult).
// setprio(1) around MFMA clusters. VGPR 40 -> 3 blocks/CU. NOTE: plain
// __launch_bounds__ — a min-waves arg makes the allocator spill (r5).
__global__ __launch_bounds__(512) void attn_kernel(
    const unsigned short* __restrict__ qb, const unsigned short* __restrict__ kb,
    const unsigned short* __restrict__ vb, const uint32_t* __restrict__ biasP,
    const uint32_t* __restrict__ maskP, unsigned short* __restrict__ ob) {
  __shared__ __align__(16) unsigned short Ks[352][40];  // [perm key row][d]
  __shared__ __align__(16) unsigned short Vt[HD][360];  // [d][key]
  // XCD swizzle: bid%8 = XCD (observed round-robin); job groups of 24 share wdx
  const int bid = blockIdx.x;
  const int job = (bid & 7) * 96 + (bid >> 3);
  const int wdx = job / 24;
  const int inner = job - wdx * 24;
  const int h = inner >> 2;
  const int b = (inner & 3) * 32 + wdx;   // preserves wdx == b & 31
  const int tid = threadIdx.x;
  const int wave = tid >> 6, lane = tid & 63;
  const int quad = lane >> 4, c = lane & 15;
  const size_t base = ((size_t)b * NH + h) * (WN * HD);
  const unsigned short* q = qb + base;
  const unsigned short* k = kb + base;
  const unsigned short* v = vb + base;
  const uint32_t* bS = biasP + (size_t)h * BMSLICE;
  const uint32_t* mS = maskP + (size_t)wdx * BMSLICE;

  // stage K with permuted rows
  for (int t = tid; t < WN * 4; t += 512) {
    int r = t >> 2, ch = t & 3;
    int kk = r & 31;
    int row = (r & ~31) + 16 * ((kk >> 2) & 1) + 4 * (kk >> 3) + (kk & 3);
    *(short8*)&Ks[row][ch * 8] = *(const short8*)(k + r * HD + ch * 8);
  }
  for (int t = tid; t < 9 * 32; t += 512) {
    int kg = WN + (t >> 5);
    int kk = kg & 31;
    int row = (kg & ~31) + 16 * ((kk >> 2) & 1) + 4 * (kk >> 3) + (kk & 3);
    Ks[row][t & 31] = 0;
  }
  // stage V transposed, natural key order
  for (int t = tid; t < WN; t += 512) {
#pragma unroll
    for (int ch = 0; ch < 4; ++ch) {
      short8 vv = *(const short8*)(v + t * HD + ch * 8);
#pragma unroll
      for (int j = 0; j < 8; ++j) Vt[ch * 8 + j][t] = vv[j];
    }
  }
  for (int t = tid; t < 9 * 32; t += 512) {
    Vt[t & 31][WN + (t >> 5)] = 0;
  }
  __syncthreads();

  // bf16 ones fragment for the row-sum MFMA
  union { short8 v8; uint32_t d[4]; } on;
  on.d[0] = on.d[1] = on.d[2] = on.d[3] = 0x3F803F80u;

  for (int qt = wave; qt < 22; qt += 8) {
    const int q0 = qt * 16;
    int qr = q0 + c; if (qr > WN - 1) qr = WN - 1;
    const short8 qf = *(const short8*)(q + qr * HD + quad * 8);
    const uint32_t* bPtr = bS + ((size_t)quad * 352 + q0 + c) * 4;
    const uint32_t* mPtr = mS + ((size_t)quad * 352 + q0 + c) * 4;

    f32x4 o0 = (f32x4){0.f, 0.f, 0.f, 0.f};
    f32x4 o1 = (f32x4){0.f, 0.f, 0.f, 0.f};
    f32x4 accl = (f32x4){0.f, 0.f, 0.f, 0.f};
    uint4 bw = *(const uint4*)bPtr;
    uint4 mw = *(const uint4*)mPtr;
#pragma unroll 1
    for (int kc = 0; kc < 11; ++kc) {
      bPtr += BMKC; mPtr += BMKC;
      uint4 bwN = *(const uint4*)bPtr;   // kc=10: mapped garbage, unused
      uint4 mwN = *(const uint4*)mPtr;
      // C-operand = log2e*(bias+mask) for this lane's 8 keys
      f32x4 cc0, cc1;
      {
        __half2 s2; float2 f;
        s2 = __hadd2(*(__half2*)&bw.x, *(__half2*)&mw.x);
        f = __half22float2(s2); cc0[0] = f.x; cc1[0] = f.y;
        s2 = __hadd2(*(__half2*)&bw.y, *(__half2*)&mw.y);
        f = __half22float2(s2); cc0[1] = f.x; cc1[1] = f.y;
        s2 = __hadd2(*(__half2*)&bw.z, *(__half2*)&mw.z);
        f = __half22float2(s2); cc0[2] = f.x; cc1[2] = f.y;
        s2 = __hadd2(*(__half2*)&bw.w, *(__half2*)&mw.w);
        f = __half22float2(s2); cc0[3] = f.x; cc1[3] = f.y;
      }
      const int k0 = kc * 32;
      short8 kf0 = *(const short8*)&Ks[k0 + c][quad * 8];
      short8 kf1 = *(const short8*)&Ks[k0 + 16 + c][quad * 8];
      __builtin_amdgcn_s_setprio(1);
      f32x4 s0 = __builtin_amdgcn_mfma_f32_16x16x32_bf16(kf0, qf, cc0, 0, 0, 0);
      f32x4 s1 = __builtin_amdgcn_mfma_f32_16x16x32_bf16(kf1, qf, cc1, 0, 0, 0);
      __builtin_amdgcn_s_setprio(0);
      // scores in log2 domain -> direct v_exp_f32 (2^x), unnormalized;
      // OOB keys carry -30000 -> exp2==0
      float p0 = __builtin_amdgcn_exp2f(s0[0]), p1 = __builtin_amdgcn_exp2f(s0[1]);
      float p2 = __builtin_amdgcn_exp2f(s0[2]), p3 = __builtin_amdgcn_exp2f(s0[3]);
      float p4 = __builtin_amdgcn_exp2f(s1[0]), p5 = __builtin_amdgcn_exp2f(s1[1]);
      float p6 = __builtin_amdgcn_exp2f(s1[2]), p7 = __builtin_amdgcn_exp2f(s1[3]);
      union { short8 v8; uint32_t d[4]; } pf;
      pf.d[0] = pk2bf(p0, p1);
      pf.d[1] = pk2bf(p2, p3);
      pf.d[2] = pk2bf(p4, p5);
      pf.d[3] = pk2bf(p6, p7);
      short8 vf0 = *(const short8*)&Vt[c][k0 + quad * 8];
      short8 vf1 = *(const short8*)&Vt[16 + c][k0 + quad * 8];
      __builtin_amdgcn_s_setprio(1);
      o0 = __builtin_amdgcn_mfma_f32_16x16x32_bf16(pf.v8, vf0, o0, 0, 0, 0);
      o1 = __builtin_amdgcn_mfma_f32_16x16x32_bf16(pf.v8, vf1, o1, 0, 0, 0);
      accl = __builtin_amdgcn_mfma_f32_16x16x32_bf16(pf.v8, on.v8, accl, 0, 0, 0);
      __builtin_amdgcn_s_setprio(0);
      bw = bwN; mw = mwN;
    }

    // Epilogue: O rows m=quad*4+r are queries q0+m; accl[r] = l for that
    // query at the SAME lane (no shuffles). Store into swizzled tile layout:
    // tile (M>>7, kt=h), row M&127, chunk lch ^ ((row>>1)&3) -- proj reads
    // via global_load_lds.
#pragma unroll
    for (int r = 0; r < 4; ++r) {
      int n = q0 + quad * 4 + r;
      if (n < WN) {
        float inv = 1.0f / accl[r];
        int M = b * WN + n;
        int rloc = M & 127;
        int xr = (rloc >> 1) & 3;
        size_t base2 = (((size_t)(M >> 7) * 6 + h) << 12) + rloc * 32;
        ob[base2 + (((c >> 3) ^ xr) << 3) + (c & 7)] = f2bf(o0[r] * inv);
        ob[base2 + ((((c >> 3) | 2) ^ xr) << 3) + (c & 7)] = f2bf(o1[r] * inv);
      }
    }
  }
}

// ---------------- output projection (r8): same 2-phase pipeline. 32KB LDS
// (2 x {XL 4KB + WL 12KB}); grid 686 = all blocks resident regardless, so
// the LDS bump costs nothing. One vmcnt(0)+s_barrier per tile, DMA of
// tile k+1 overlaps the 12 MFMAs of tile k.
__global__ __launch_bounds__(256) void proj_kernel(
    const unsigned short* __restrict__ obp, const unsigned short* __restrict__ wpb,
    const float* __restrict__ bvec, float* __restrict__ out) {
  __shared__ __align__(16) unsigned short SL[16384];   // 32KB, two 8192 bufs
  const int tid = threadIdx.x;
  const int wave = tid >> 6, lane = tid & 63;
  const int quad = lane >> 4, c = lane & 15;
  const int m0 = blockIdx.x * 64;
  const int mb = blockIdx.x >> 1;
  const int r0 = (blockIdx.x & 1) * 64;
  const int chk = (quad ^ ((c >> 1) & 3)) * 8;

  f32x4 acc[12];
#pragma unroll
  for (int j = 0; j < 12; ++j) acc[j] = (f32x4){0.f, 0.f, 0.f, 0.f};

  auto STAGE = [&](unsigned short* buf, int kt) {
    const unsigned short* gx =
        obp + (((size_t)mb * 6 + kt) << 12) + r0 * 32 + tid * 8;
    const unsigned short* gw = wpb + (size_t)kt * 6144 + tid * 8;
    unsigned short* lx = buf + (size_t)wave * 512;          // XL: 2048 shorts
    unsigned short* lw = buf + 2048 + (size_t)wave * 512;   // WL: 6144 shorts
    gload16(gx, lx);
    gload16(gw, lw);
    gload16(gw + 2048, lw + 2048);
    gload16(gw + 4096, lw + 4096);
  };
  auto COMPUTE = [&](const unsigned short* buf) {
    const unsigned short* XLb = buf;
    const unsigned short* WLb = buf + 2048;
    short8 af = *(const short8*)&XLb[(wave * 16 + c) * 32 + chk];
#pragma unroll
    for (int j = 0; j < 12; ++j) {
      short8 bfr = *(const short8*)&WLb[(j * 16 + c) * 32 + chk];
      acc[j] = __builtin_amdgcn_mfma_f32_16x16x32_bf16(af, bfr, acc[j], 0, 0, 0);
    }
  };

  unsigned short* B0 = SL;
  unsigned short* B1 = SL + 8192;
  STAGE(B0, 0);
  pipe_bar();
#pragma unroll
  for (int p = 0; p < 3; ++p) {
    STAGE(B1, 2 * p + 1);
    COMPUTE(B0);
    pipe_bar();
    if (p < 2) STAGE(B0, 2 * p + 2);
    COMPUTE(B1);
    pipe_bar();
  }

#pragma unroll
  for (int j = 0; j < 12; ++j) {
    int col = j * 16 + c;
    float bn = bvec[col];
#pragma unroll
    for (int r = 0; r < 4; ++r) {
      int m = m0 + wave * 16 + quad * 4 + r;
      out[(size_t)m * CD + col] = acc[j][r] + bn;
    }
  }
}

extern "C" void kernel_launch(void* const* d_in, const int* in_sizes, int n_in,
                              void* d_out, int out_size, void* d_ws, size_t ws_size,
                              hipStream_t stream) {
  const float* x      = (const float*)d_in[0];
  const float* mask   = (const float*)d_in[1];
  const float* qkv_w  = (const float*)d_in[2];
  const float* qkv_b  = (const float*)d_in[3];
  const float* proj_w = (const float*)d_in[4];
  const float* proj_b = (const float*)d_in[5];
  const float* rpb    = (const float*)d_in[6];
  const int*   rel    = (const int*)d_in[7];
  float* out = (float*)d_out;

  char* ws = (char*)d_ws;
  uint32_t* biasP = (uint32_t*)ws;                       // 6*61952*4 = 1,486,848
  size_t off = 1486848;
  uint32_t* maskP = (uint32_t*)(ws + off); off += 7929856;   // 32*61952*4
  unsigned short* qb = (unsigned short*)(ws + off); off += 16859136;
  unsigned short* kb = (unsigned short*)(ws + off); off += 16859136;
  unsigned short* vb = (unsigned short*)(ws + off); off += 16859136;
  unsigned short* wqb = (unsigned short*)(ws + off); off += 221184;
  unsigned short* wpb = (unsigned short*)(ws + off); off += 73728;
  unsigned short* xb  = (unsigned short*)(ws + off); off += 16859136;
  // obuf aliases xb: qkv finishes reading xb before attn writes it
  // (stream-ordered); prep rewrites xb each replay iteration.
  unsigned short* obuf = xb;

  hipLaunchKernelGGL(prep_kernel, dim3(264 + 352 + 54 + 18 + 4116), dim3(256),
                     0, stream,
                     qkv_w, proj_w, wqb, wpb, rel, rpb, mask, biasP, maskP, x, xb);
  hipLaunchKernelGGL(qkv_kernel, dim3(343, 3), dim3(256), 0, stream,
                     xb, wqb, qkv_b, qb, kb, vb);
  hipLaunchKernelGGL(attn_kernel, dim3(NH * NB), dim3(512), 0, stream,
                     qb, kb, vb, biasP, maskP, obuf);
  hipLaunchKernelGGL(proj_kernel, dim3(686), dim3(256), 0, stream,
                     obuf, wpb, proj_b, out);
}